// Round 10
// baseline (754.189 us; speedup 1.0000x reference)
//
#include <hip/hip_runtime.h>
#include <math.h>

#define N_NODES 50000
#define N_EDGES 400000
#define C 32
#define NB 8
#define HID 64
#define NL 2
#define NG 64
#define RMAXF 5.0f
#define EPSF 1e-5f
#define TBL 4096
#define NBLK_N ((N_NODES + 255) / 256)   // 196

__device__ __forceinline__ float silu_f(float x) { return x / (1.0f + __expf(-x)); }
__device__ __forceinline__ float sigmoid_f(float x) { return 1.0f / (1.0f + __expf(-x)); }
__device__ __forceinline__ void atomAddF(float* p, float val) {
  __hip_atomic_fetch_add(p, val, __ATOMIC_RELAXED, __HIP_MEMORY_SCOPE_AGENT);
}
__device__ __forceinline__ void atomAddD(double* p, double val) {
  __hip_atomic_fetch_add(p, val, __ATOMIC_RELAXED, __HIP_MEMORY_SCOPE_AGENT);
}

// ---------------- edge geometry: basis (fb only), dist (E), unit dir Y1 (E,3) -----
__global__ __launch_bounds__(256) void k_edge_geom(
    const float* __restrict__ pos, const int* __restrict__ ei,
    const float* __restrict__ freqs,
    float* __restrict__ basis, float* __restrict__ Y1, float* __restrict__ distb)
{
  int e = blockIdx.x * 256 + threadIdx.x;
  if (e >= N_EDGES) return;
  int s = ei[e], d = ei[N_EDGES + e];
  float vx = pos[d*3+0] - pos[s*3+0];
  float vy = pos[d*3+1] - pos[s*3+1];
  float vz = pos[d*3+2] - pos[s*3+2];
  float dist = sqrtf(vx*vx + vy*vy + vz*vz);
  float invd = 1.0f / fmaxf(dist, 1e-9f);
  Y1[e*3+0] = vx*invd; Y1[e*3+1] = vy*invd; Y1[e*3+2] = vz*invd;
  distb[e] = dist;
  float x = fminf(fmaxf(dist * (1.0f/RMAXF), 0.0f), 1.0f);
  float x2 = x*x, x3 = x2*x;
  float cut = 1.0f - x3 * (10.0f - 15.0f*x + 6.0f*x2);
  if (dist > RMAXF) cut = 0.0f;
  float rinv = cut / fmaxf(dist, 1e-6f);
  #pragma unroll
  for (int k = 0; k < NB; k++)
    basis[e*NB + k] = sinf(freqs[k] * dist) * rinv;
}

// ---------------- node init ----------------
__global__ __launch_bounds__(256) void k_node_init(
    const int* __restrict__ species, const float* __restrict__ emb, float* __restrict__ s)
{
  int i = blockIdx.x * 256 + threadIdx.x;
  if (i >= N_NODES * C) return;
  int n = i >> 5, c = i & 31;
  s[i] = emb[species[n]*C + c];
}

// ---------------- CSR build ----------------
__global__ __launch_bounds__(256) void k_hist(const int* __restrict__ ei, int* __restrict__ counts)
{
  int e = blockIdx.x * 256 + threadIdx.x;
  if (e >= N_EDGES) return;
  atomicAdd(&counts[ei[N_EDGES + e]], 1);
}

__global__ __launch_bounds__(256) void k_scanA(const int* __restrict__ counts, int* __restrict__ bsum)
{
  __shared__ int sh[256];
  int i = blockIdx.x * 256 + threadIdx.x;
  int x = (i < N_NODES) ? counts[i] : 0;
  sh[threadIdx.x] = x;
  __syncthreads();
  for (int off = 128; off > 0; off >>= 1) {
    if (threadIdx.x < off) sh[threadIdx.x] += sh[threadIdx.x + off];
    __syncthreads();
  }
  if (threadIdx.x == 0) bsum[blockIdx.x] = sh[0];
}

__global__ void k_scanB(int* __restrict__ bsum)
{
  if (threadIdx.x == 0) {
    int acc = 0;
    for (int b = 0; b < NBLK_N; b++) { int t = bsum[b]; bsum[b] = acc; acc += t; }
  }
}

__global__ __launch_bounds__(256) void k_scanC(const int* __restrict__ counts,
                                               const int* __restrict__ bsum,
                                               int* __restrict__ row_start)
{
  __shared__ int sh[256];
  int i = blockIdx.x * 256 + threadIdx.x;
  int x = (i < N_NODES) ? counts[i] : 0;
  sh[threadIdx.x] = x;
  __syncthreads();
  for (int off = 1; off < 256; off <<= 1) {
    int y = (threadIdx.x >= off) ? sh[threadIdx.x - off] : 0;
    __syncthreads();
    sh[threadIdx.x] += y;
    __syncthreads();
  }
  if (i < N_NODES) row_start[i] = bsum[blockIdx.x] + sh[threadIdx.x] - x; // exclusive
}

// scatter: pre-gather dist, Y1, src into dst-sorted order
__global__ __launch_bounds__(256) void k_scatter(const int* __restrict__ ei,
                                                 const int* __restrict__ row_start,
                                                 int* __restrict__ cursor,
                                                 const float* __restrict__ Y1,
                                                 const float* __restrict__ distb,
                                                 int* __restrict__ srcs,
                                                 float* __restrict__ Y1s,
                                                 float* __restrict__ dist_s)
{
  int e = blockIdx.x * 256 + threadIdx.x;
  if (e >= N_EDGES) return;
  int d = ei[N_EDGES + e];
  int p = row_start[d] + atomicAdd(&cursor[d], 1);
  srcs[p] = ei[e];
  dist_s[p] = distb[e];
  Y1s[p*3+0] = Y1[e*3+0];
  Y1s[p*3+1] = Y1[e*3+1];
  Y1s[p*3+2] = Y1[e*3+2];
}

// ---------------- radial-MLP tabulation ----------------
__global__ __launch_bounds__(256) void k_table_h(
    const float* __restrict__ freqs,
    const float* __restrict__ rW1, const float* __restrict__ rb1,
    const float* __restrict__ rW2, const float* __restrict__ rb2,
    float* __restrict__ h2tab)                 // [NL*TBL*HID]
{
  int idx = blockIdx.x * 256 + threadIdx.x;    // [NL*TBL]
  if (idx >= NL * TBL) return;
  int l = idx / TBL, i = idx - l * TBL;
  float d = (float)i * (RMAXF / (float)(TBL - 1));
  float x = fminf(fmaxf(d * (1.0f/RMAXF), 0.0f), 1.0f);
  float x2 = x*x, x3 = x2*x;
  float cut = 1.0f - x3 * (10.0f - 15.0f*x + 6.0f*x2);
  float rinv = cut / fmaxf(d, 1e-6f);
  float bas[NB];
  #pragma unroll
  for (int k = 0; k < NB; k++) bas[k] = sinf(freqs[k] * d) * rinv;

  const float* W1 = rW1 + l*NB*HID;
  const float* B1 = rb1 + l*HID;
  const float* W2 = rW2 + l*HID*HID;
  const float* B2 = rb2 + l*HID;

  float h2[HID];
  #pragma unroll
  for (int j = 0; j < HID; j++) h2[j] = B2[j];
  #pragma unroll 2
  for (int k = 0; k < HID; k++) {
    float t = B1[k];
    #pragma unroll
    for (int b = 0; b < NB; b++) t = fmaf(bas[b], W1[b*HID + k], t);
    float h1k = silu_f(t);
    const float* r = W2 + k*HID;
    #pragma unroll
    for (int j = 0; j < HID; j++) h2[j] = fmaf(h1k, r[j], h2[j]);
  }
  float* out = h2tab + (size_t)idx * HID;
  #pragma unroll
  for (int j = 0; j < HID; j++) out[j] = silu_f(h2[j]);
}

__global__ __launch_bounds__(256) void k_table_w(
    const float* __restrict__ h2tab,
    const float* __restrict__ rW3, const float* __restrict__ rb3,
    float* __restrict__ wtab)                  // [NL*TBL*128]
{
  int idx = blockIdx.x * 256 + threadIdx.x;    // [NL*TBL*16]
  if (idx >= NL * TBL * 16) return;
  int chunk = idx & 15;
  int row   = idx >> 4;                        // l*TBL + i
  int l     = row / TBL;
  const float* h2 = h2tab + (size_t)row * HID;
  const float* W3 = rW3 + l*HID*4*C + chunk*8;
  const float* B3 = rb3 + l*4*C + chunk*8;
  float a[8];
  #pragma unroll
  for (int ci = 0; ci < 8; ci++) a[ci] = B3[ci];
  #pragma unroll 4
  for (int k = 0; k < HID; k++) {
    float h = h2[k];
    #pragma unroll
    for (int ci = 0; ci < 8; ci++) a[ci] = fmaf(h, W3[k*4*C + ci], a[ci]);
  }
  float* out = wtab + (size_t)row * 128 + chunk*8;
  #pragma unroll
  for (int ci = 0; ci < 8; ci++) out[ci] = a[ci];
}

// ---------------- aggregate (table lerp) + gate + self-int + BN stats -------------
// ONE NODE PER 64-LANE WAVE: c = lane&31, h = lane>>5. Half-wave h handles edges
// i = h, h+2, ... (serial chain halved); inside each half, manual 2x unroll (edges
// i, i+2 loaded as independent batches) -> 4x memory-level parallelism vs r9
// (which sat at VALUBusy 14%, VGPR 28: latency-bound, zero lookahead).
// Halves merged via __shfl_xor(...,32); writes/BN from h==0 only.
__global__ __launch_bounds__(256) void k_agg_update(
    const float* __restrict__ tb,              // this layer's wtab [TBL][128]
    const float* __restrict__ dist_s, const float* __restrict__ Y1s,
    const int* __restrict__ srcs,
    const int* __restrict__ row_start, const int* __restrict__ counts,
    const float* __restrict__ s, const float* __restrict__ v,
    const float* __restrict__ Wss, const float* __restrict__ bss,
    const float* __restrict__ Wvv,
    float* __restrict__ s_new, float* __restrict__ v_new,
    double* __restrict__ bn_sums)
{
  __shared__ float lacc[3*C];
  int t = blockIdx.x * 256 + threadIdx.x;
  int n = t >> 6;                              // node per 64-lane wave
  int lane = threadIdx.x & 63;
  int c = lane & 31;
  int h = lane >> 5;
  if (threadIdx.x < 3*C) lacc[threadIdx.x] = 0.0f;
  __syncthreads();

  const float SCALE = (float)(TBL - 1) / RMAXF;
  float asf = 0.0f, asg = 0.0f, av0 = 0.0f, av1 = 0.0f, av2 = 0.0f;
  int beg = row_start[n], cnt = counts[n];

  int i = h;
  // ---- 2x unrolled: edges i and i+2 (independent load batches) ----
  for (; i + 2 < cnt; i += 4) {
    int pA = beg + i, pB = beg + i + 2;
    float dA = dist_s[pA],  dB = dist_s[pB];
    int srcA = srcs[pA],    srcB = srcs[pB];
    float yA0 = Y1s[pA*3+0], yA1 = Y1s[pA*3+1], yA2 = Y1s[pA*3+2];
    float yB0 = Y1s[pB*3+0], yB1 = Y1s[pB*3+1], yB2 = Y1s[pB*3+2];

    float tsA = fminf(dA, RMAXF) * SCALE;
    int t0A = (int)tsA; t0A = t0A > TBL-2 ? TBL-2 : t0A;
    float frA = tsA - (float)t0A;
    float tsB = fminf(dB, RMAXF) * SCALE;
    int t0B = (int)tsB; t0B = t0B > TBL-2 ? TBL-2 : t0B;
    float frB = tsB - (float)t0B;

    const float* rA0 = tb + (size_t)t0A * 128 + c;
    const float* rA1 = rA0 + 128;
    const float* rB0 = tb + (size_t)t0B * 128 + c;
    const float* rB1 = rB0 + 128;

    float a00 = rA0[0],  a01 = rA1[0];
    float a10 = rA0[32], a11 = rA1[32];
    float a20 = rA0[64], a21 = rA1[64];
    float a30 = rA0[96], a31 = rA1[96];
    float b00 = rB0[0],  b01 = rB1[0];
    float b10 = rB0[32], b11 = rB1[32];
    float b20 = rB0[64], b21 = rB1[64];
    float b30 = rB0[96], b31 = rB1[96];

    float xsA = s[srcA*C + c];
    const float* vpA = v + (size_t)(srcA*C + c)*3;
    float xvA0 = vpA[0], xvA1 = vpA[1], xvA2 = vpA[2];
    float xsB = s[srcB*C + c];
    const float* vpB = v + (size_t)(srcB*C + c)*3;
    float xvB0 = vpB[0], xvB1 = vpB[1], xvB2 = vpB[2];

    float w1A = fmaf(frA, a01-a00, a00);
    float w2A = fmaf(frA, a11-a10, a10);
    float w3A = fmaf(frA, a21-a20, a20);
    float w4A = fmaf(frA, a31-a30, a30);
    asf = fmaf(w1A, xsA, asf);
    asg = fmaf(w2A, xvA0*yA0 + xvA1*yA1 + xvA2*yA2, asg);
    float w3xsA = w3A * xsA;
    av0 += fmaf(w3xsA, yA0, w4A*xvA0);
    av1 += fmaf(w3xsA, yA1, w4A*xvA1);
    av2 += fmaf(w3xsA, yA2, w4A*xvA2);

    float w1B = fmaf(frB, b01-b00, b00);
    float w2B = fmaf(frB, b11-b10, b10);
    float w3B = fmaf(frB, b21-b20, b20);
    float w4B = fmaf(frB, b31-b30, b30);
    asf = fmaf(w1B, xsB, asf);
    asg = fmaf(w2B, xvB0*yB0 + xvB1*yB1 + xvB2*yB2, asg);
    float w3xsB = w3B * xsB;
    av0 += fmaf(w3xsB, yB0, w4B*xvB0);
    av1 += fmaf(w3xsB, yB1, w4B*xvB1);
    av2 += fmaf(w3xsB, yB2, w4B*xvB2);
  }
  // ---- remainder ----
  for (; i < cnt; i += 2) {
    int p = beg + i;
    float d  = dist_s[p];
    int src = srcs[p];
    float y0 = Y1s[p*3+0], y1 = Y1s[p*3+1], y2 = Y1s[p*3+2];
    float ts = fminf(d, RMAXF) * SCALE;
    int   t0 = (int)ts; t0 = t0 > TBL-2 ? TBL-2 : t0;
    float fr = ts - (float)t0;
    const float* r0 = tb + (size_t)t0 * 128 + c;
    const float* r1 = r0 + 128;
    float w1 = fmaf(fr, r1[0]  - r0[0],  r0[0]);
    float w2 = fmaf(fr, r1[32] - r0[32], r0[32]);
    float w3 = fmaf(fr, r1[64] - r0[64], r0[64]);
    float w4 = fmaf(fr, r1[96] - r0[96], r0[96]);
    float xs = s[src*C + c];
    const float* vp = v + (size_t)(src*C + c)*3;
    float xv0 = vp[0], xv1 = vp[1], xv2 = vp[2];
    asf = fmaf(w1, xs, asf);
    asg = fmaf(w2, xv0*y0 + xv1*y1 + xv2*y2, asg);
    float w3xs = w3 * xs;
    av0 += fmaf(w3xs, y0, w4*xv0);
    av1 += fmaf(w3xs, y1, w4*xv1);
    av2 += fmaf(w3xs, y2, w4*xv2);
  }

  // merge the two halves (both end up with the full sums)
  asf += __shfl_xor(asf, 32);
  asg += __shfl_xor(asg, 32);
  av0 += __shfl_xor(av0, 32);
  av1 += __shfl_xor(av1, 32);
  av2 += __shfl_xor(av2, 32);

  float sgv  = silu_f(asf);
  float gate = sigmoid_f(asg);
  float vg0 = gate*av0, vg1 = gate*av1, vg2 = gate*av2;

  float sn = bss[c];
  float vm0 = 0.0f, vm1 = 0.0f, vm2 = 0.0f;
  #pragma unroll
  for (int k = 0; k < C; k++) {
    float a  = __shfl(sgv, k, 32);
    sn = fmaf(a, Wss[k*C + c], sn);
    float wv = Wvv[k*C + c];
    vm0 = fmaf(__shfl(vg0, k, 32), wv, vm0);
    vm1 = fmaf(__shfl(vg1, k, 32), wv, vm1);
    vm2 = fmaf(__shfl(vg2, k, 32), wv, vm2);
  }

  if (h == 0) {
    s_new[n*C + c] = sn;
    float* vo = v_new + (size_t)(n*C + c)*3;
    vo[0] = vm0; vo[1] = vm1; vo[2] = vm2;
    float vn2 = vm0*vm0 + vm1*vm1 + vm2*vm2;
    atomicAdd(&lacc[c],       sn);
    atomicAdd(&lacc[C + c],   sn*sn);
    atomicAdd(&lacc[2*C + c], vn2);
  }
  __syncthreads();
  if (threadIdx.x < 3*C) atomAddD(&bn_sums[threadIdx.x], (double)lacc[threadIdx.x]);
}

// ---------------- BN scales ----------------
__global__ void k_bn_scales(const double* __restrict__ bn_sums,
                            const float* __restrict__ gs, const float* __restrict__ gv,
                            float* __restrict__ scales)
{
  int m = threadIdx.x;
  if (m >= C) return;
  double S1 = bn_sums[m], S2 = bn_sums[C + m], VN = bn_sums[2*C + m];
  double mu  = S1 / (double)N_NODES;
  double var = S2 / (double)N_NODES - mu*mu;
  double vn2 = VN / (3.0 * (double)N_NODES);
  scales[m]       = (float)mu;
  scales[C + m]   = gs[m] / sqrtf((float)var + EPSF);
  scales[2*C + m] = gv[m] / sqrtf((float)vn2 + EPSF);
}

// ---------------- apply BN + residual ----------------
__global__ __launch_bounds__(256) void k_apply(
    const float* __restrict__ s_new, const float* __restrict__ v_new,
    const float* __restrict__ scales, const float* __restrict__ bn_bs,
    float* __restrict__ s, float* __restrict__ v)
{
  int i = blockIdx.x * 256 + threadIdx.x;
  if (i >= N_NODES * C) return;
  int c = i & 31;
  s[i] += (s_new[i] - scales[c]) * scales[C + c] + bn_bs[c];
  float vs = scales[2*C + c];
  v[(size_t)i*3+0] += v_new[(size_t)i*3+0] * vs;
  v[(size_t)i*3+1] += v_new[(size_t)i*3+1] * vs;
  v[(size_t)i*3+2] += v_new[(size_t)i*3+2] * vs;
}

// ---------------- readout ----------------
__global__ __launch_bounds__(256) void k_readout(
    const float* __restrict__ s, const int* __restrict__ species,
    const int* __restrict__ batch,
    const float* __restrict__ W_out, const float* __restrict__ b_out,
    const float* __restrict__ atom_ref, float* __restrict__ out)
{
  __shared__ float acc[NG];
  if (threadIdx.x < NG) acc[threadIdx.x] = 0.0f;
  __syncthreads();
  int n = blockIdx.x * 256 + threadIdx.x;
  if (n < N_NODES) {
    float e = b_out[0] + atom_ref[species[n]];
    #pragma unroll
    for (int c = 0; c < C; c++) e = fmaf(s[n*C + c], W_out[c], e);
    atomicAdd(&acc[batch[n]], e);
  }
  __syncthreads();
  if (threadIdx.x < NG) {
    float a = acc[threadIdx.x];
    if (a != 0.0f) atomAddF(&out[threadIdx.x], a);
  }
}

// ================= FALLBACK (atomic path, used only if ws too small) ==========
__global__ __launch_bounds__(256) void k_edge_msg_fb(
    const float* __restrict__ basis, const float* __restrict__ Y1,
    const int* __restrict__ ei,
    const float* __restrict__ s, const float* __restrict__ v,
    const float* __restrict__ rW1, const float* __restrict__ rb1,
    const float* __restrict__ rW2, const float* __restrict__ rb2,
    const float* __restrict__ rW3, const float* __restrict__ rb3,
    float* __restrict__ agg_sf, float* __restrict__ agg_sg, float* __restrict__ agg_v)
{
  int e = blockIdx.x * 256 + threadIdx.x;
  if (e >= N_EDGES) return;
  int src = ei[e], dst = ei[N_EDGES + e];
  const float4 b0 = *(const float4*)(basis + (size_t)e*NB);
  const float4 b1 = *(const float4*)(basis + (size_t)e*NB + 4);
  float bas[NB] = {b0.x, b0.y, b0.z, b0.w, b1.x, b1.y, b1.z, b1.w};
  float h2[HID];
  #pragma unroll
  for (int j = 0; j < HID; j++) h2[j] = rb2[j];
  #pragma unroll 2
  for (int k = 0; k < HID; k++) {
    float t = rb1[k];
    #pragma unroll
    for (int b = 0; b < NB; b++) t = fmaf(bas[b], rW1[b*HID + k], t);
    float h1k = silu_f(t);
    const float* r = rW2 + k*HID;
    #pragma unroll
    for (int j = 0; j < HID; j++) h2[j] = fmaf(h1k, r[j], h2[j]);
  }
  #pragma unroll
  for (int j = 0; j < HID; j++) h2[j] = silu_f(h2[j]);
  float y0 = Y1[e*3+0], y1 = Y1[e*3+1], y2 = Y1[e*3+2];
  #pragma unroll 1
  for (int cb = 0; cb < 16; cb++) {
    float a[8];
    #pragma unroll
    for (int ci = 0; ci < 8; ci++) a[ci] = rb3[cb*8 + ci];
    #pragma unroll
    for (int k = 0; k < HID; k++) {
      float h = h2[k];
      #pragma unroll
      for (int ci = 0; ci < 8; ci++) a[ci] = fmaf(h, rW3[k*4*C + cb*8 + ci], a[ci]);
    }
    #pragma unroll
    for (int ci = 0; ci < 8; ci++) {
      int o = cb*8 + ci;
      int path = o >> 5;
      int c = o & 31;
      float xs = s[src*C + c];
      const float* vp = v + (size_t)(src*C + c)*3;
      float xv0 = vp[0], xv1 = vp[1], xv2 = vp[2];
      if (path == 0) {
        atomAddF(&agg_sf[dst*C + c], a[ci] * xs);
      } else if (path == 1) {
        atomAddF(&agg_sg[dst*C + c], a[ci] * (xv0*y0 + xv1*y1 + xv2*y2));
      } else if (path == 2) {
        float w3xs = a[ci] * xs;
        float* ap = agg_v + (size_t)(dst*C + c)*3;
        atomAddF(ap+0, w3xs*y0); atomAddF(ap+1, w3xs*y1); atomAddF(ap+2, w3xs*y2);
      } else {
        float* ap = agg_v + (size_t)(dst*C + c)*3;
        atomAddF(ap+0, a[ci]*xv0); atomAddF(ap+1, a[ci]*xv1); atomAddF(ap+2, a[ci]*xv2);
      }
    }
  }
}

__global__ __launch_bounds__(256) void k_node_update_fb(
    const float* __restrict__ agg_sf, const float* __restrict__ agg_sg,
    const float* __restrict__ agg_v,
    const float* __restrict__ Wss, const float* __restrict__ bss,
    const float* __restrict__ Wvv,
    float* __restrict__ s_new, float* __restrict__ v_new,
    double* __restrict__ bn_sums)
{
  __shared__ float lacc[3*C];
  int t = blockIdx.x * 256 + threadIdx.x;
  int n = t >> 5;
  int c = t & 31;
  if (threadIdx.x < 3*C) lacc[threadIdx.x] = 0.0f;
  __syncthreads();
  float asf = agg_sf[n*C + c];
  float asg = agg_sg[n*C + c];
  const float* ap = agg_v + (size_t)(n*C + c)*3;
  float av0 = ap[0], av1 = ap[1], av2 = ap[2];
  float sgv = silu_f(asf);
  float gate = sigmoid_f(asg);
  float vg0 = gate*av0, vg1 = gate*av1, vg2 = gate*av2;
  float sn = bss[c];
  float vm0 = 0.0f, vm1 = 0.0f, vm2 = 0.0f;
  #pragma unroll
  for (int k = 0; k < C; k++) {
    float a  = __shfl(sgv, k, 32);
    sn = fmaf(a, Wss[k*C + c], sn);
    float wv = Wvv[k*C + c];
    vm0 = fmaf(__shfl(vg0, k, 32), wv, vm0);
    vm1 = fmaf(__shfl(vg1, k, 32), wv, vm1);
    vm2 = fmaf(__shfl(vg2, k, 32), wv, vm2);
  }
  s_new[n*C + c] = sn;
  float* vo = v_new + (size_t)(n*C + c)*3;
  vo[0] = vm0; vo[1] = vm1; vo[2] = vm2;
  float vn2 = vm0*vm0 + vm1*vm1 + vm2*vm2;
  atomicAdd(&lacc[c], sn);
  atomicAdd(&lacc[C + c], sn*sn);
  atomicAdd(&lacc[2*C + c], vn2);
  __syncthreads();
  if (threadIdx.x < 3*C) atomAddD(&bn_sums[threadIdx.x], (double)lacc[threadIdx.x]);
}

extern "C" void kernel_launch(void* const* d_in, const int* in_sizes, int n_in,
                              void* d_out, int out_size, void* d_ws, size_t ws_size,
                              hipStream_t stream)
{
  const int*   species  = (const int*)  d_in[0];
  const float* pos      = (const float*)d_in[1];
  const int*   ei       = (const int*)  d_in[2];
  const int*   batch    = (const int*)  d_in[3];
  const float* emb      = (const float*)d_in[4];
  const float* freqs    = (const float*)d_in[5];
  const float* rW1      = (const float*)d_in[6];
  const float* rb1      = (const float*)d_in[7];
  const float* rW2      = (const float*)d_in[8];
  const float* rb2      = (const float*)d_in[9];
  const float* rW3      = (const float*)d_in[10];
  const float* rb3      = (const float*)d_in[11];
  const float* Wss      = (const float*)d_in[12];
  const float* bss      = (const float*)d_in[13];
  const float* Wvv      = (const float*)d_in[14];
  const float* bn_gs    = (const float*)d_in[15];
  const float* bn_bs    = (const float*)d_in[16];
  const float* bn_gv    = (const float*)d_in[17];
  const float* W_out    = (const float*)d_in[18];
  const float* b_out    = (const float*)d_in[19];
  const float* atom_ref = (const float*)d_in[20];

  float* ws = (float*)d_ws;
  size_t off = 0;
  float* basis  = ws + off; off += (size_t)N_EDGES * NB;     // fb path only
  float* Y1     = ws + off; off += (size_t)N_EDGES * 3;
  float* distb  = ws + off; off += (size_t)N_EDGES;
  float* s      = ws + off; off += (size_t)N_NODES * C;
  float* v      = ws + off; off += (size_t)N_NODES * C * 3;
  float* s_new  = ws + off; off += (size_t)N_NODES * C;
  float* v_new  = ws + off; off += (size_t)N_NODES * C * 3;
  double* bn_sums = (double*)(ws + off); off += 192;
  float* scales = ws + off; off += 96;

  // --- region A (sorted + table path) ---
  size_t ra = off;
  float* Y1s      = ws + ra;            ra += (size_t)N_EDGES * 3;
  float* dist_s   = ws + ra;            ra += (size_t)N_EDGES;
  int*   srcs     = (int*)(ws + ra);    ra += N_EDGES;
  int*   counts   = (int*)(ws + ra);    ra += N_NODES;
  int*   row_start= (int*)(ws + ra);    ra += N_NODES;
  int*   cursor   = (int*)(ws + ra);    ra += N_NODES;
  int*   bsum     = (int*)(ws + ra);    ra += 256;
  float* h2tab    = ws + ra;            ra += (size_t)NL * TBL * HID;
  float* wtab     = ws + ra;            ra += (size_t)NL * TBL * 128;
  size_t req_sorted = ra * 4;

  // --- region B (fallback atomic path, aliases region A) ---
  size_t rb = off;
  float* agg_sf = ws + rb; rb += (size_t)N_NODES * C;
  float* agg_sg = ws + rb; rb += (size_t)N_NODES * C;
  float* agg_v  = ws + rb; rb += (size_t)N_NODES * C * 3;

  dim3 b256(256);
  const int gE  = (N_EDGES + 255) / 256;
  const int gNC = (N_NODES * C + 255) / 256;
  const int gN  = (N_NODES + 255) / 256;

  hipMemsetAsync(v, 0, (size_t)N_NODES * C * 3 * sizeof(float), stream);
  k_edge_geom<<<gE, b256, 0, stream>>>(pos, ei, freqs, basis, Y1, distb);
  k_node_init<<<gNC, b256, 0, stream>>>(species, emb, s);

  if (ws_size >= req_sorted) {
    hipMemsetAsync(counts, 0, N_NODES * sizeof(int), stream);
    hipMemsetAsync(cursor, 0, N_NODES * sizeof(int), stream);
    k_hist<<<gE, b256, 0, stream>>>(ei, counts);
    k_scanA<<<NBLK_N, b256, 0, stream>>>(counts, bsum);
    k_scanB<<<1, 64, 0, stream>>>(bsum);
    k_scanC<<<NBLK_N, b256, 0, stream>>>(counts, bsum, row_start);
    k_scatter<<<gE, b256, 0, stream>>>(ei, row_start, cursor, Y1, distb,
                                       srcs, Y1s, dist_s);
    k_table_h<<<(NL*TBL)/256, b256, 0, stream>>>(freqs, rW1, rb1, rW2, rb2, h2tab);
    k_table_w<<<(NL*TBL*16)/256, b256, 0, stream>>>(h2tab, rW3, rb3, wtab);

    for (int l = 0; l < NL; l++) {
      hipMemsetAsync(bn_sums, 0, 96 * sizeof(double), stream);
      k_agg_update<<<(N_NODES*64)/256, b256, 0, stream>>>(
          wtab + (size_t)l * TBL * 128, dist_s, Y1s, srcs,
          row_start, counts, s, v, Wss + l*C*C, bss + l*C, Wvv + l*C*C,
          s_new, v_new, bn_sums);
      k_bn_scales<<<1, 64, 0, stream>>>(bn_sums, bn_gs + l*C, bn_gv + l*C, scales);
      k_apply<<<gNC, b256, 0, stream>>>(s_new, v_new, scales, bn_bs + l*C, s, v);
    }
  } else {
    for (int l = 0; l < NL; l++) {
      hipMemsetAsync(agg_sf, 0, (size_t)N_NODES * 5 * C * sizeof(float), stream);
      hipMemsetAsync(bn_sums, 0, 96 * sizeof(double), stream);
      k_edge_msg_fb<<<gE, b256, 0, stream>>>(basis, Y1, ei, s, v,
          rW1 + l*NB*HID, rb1 + l*HID, rW2 + l*HID*HID, rb2 + l*HID,
          rW3 + l*HID*4*C, rb3 + l*4*C, agg_sf, agg_sg, agg_v);
      k_node_update_fb<<<(N_NODES*C)/256, b256, 0, stream>>>(agg_sf, agg_sg, agg_v,
          Wss + l*C*C, bss + l*C, Wvv + l*C*C, s_new, v_new, bn_sums);
      k_bn_scales<<<1, 64, 0, stream>>>(bn_sums, bn_gs + l*C, bn_gv + l*C, scales);
      k_apply<<<gNC, b256, 0, stream>>>(s_new, v_new, scales, bn_bs + l*C, s, v);
    }
  }

  hipMemsetAsync(d_out, 0, NG * sizeof(float), stream);
  k_readout<<<gN, b256, 0, stream>>>(s, species, batch, W_out, b_out, atom_ref, (float*)d_out);
}

// Round 11
// 577.424 us; speedup vs baseline: 1.3061x; 1.3061x over previous
//
#include <hip/hip_runtime.h>
#include <math.h>

#define N_NODES 50000
#define N_EDGES 400000
#define C 32
#define NB 8
#define HID 64
#define NL 2
#define NG 64
#define RMAXF 5.0f
#define EPSF 1e-5f
#define TBL 4096
#define NBLK_N ((N_NODES + 255) / 256)   // 196

__device__ __forceinline__ float silu_f(float x) { return x / (1.0f + __expf(-x)); }
__device__ __forceinline__ float sigmoid_f(float x) { return 1.0f / (1.0f + __expf(-x)); }
__device__ __forceinline__ void atomAddF(float* p, float val) {
  __hip_atomic_fetch_add(p, val, __ATOMIC_RELAXED, __HIP_MEMORY_SCOPE_AGENT);
}
__device__ __forceinline__ void atomAddD(double* p, double val) {
  __hip_atomic_fetch_add(p, val, __ATOMIC_RELAXED, __HIP_MEMORY_SCOPE_AGENT);
}

// ---------------- edge geometry ----------------
__global__ __launch_bounds__(256) void k_edge_geom(
    const float* __restrict__ pos, const int* __restrict__ ei,
    const float* __restrict__ freqs,
    float* __restrict__ basis, float* __restrict__ Y1, float* __restrict__ distb)
{
  int e = blockIdx.x * 256 + threadIdx.x;
  if (e >= N_EDGES) return;
  int s = ei[e], d = ei[N_EDGES + e];
  float vx = pos[d*3+0] - pos[s*3+0];
  float vy = pos[d*3+1] - pos[s*3+1];
  float vz = pos[d*3+2] - pos[s*3+2];
  float dist = sqrtf(vx*vx + vy*vy + vz*vz);
  float invd = 1.0f / fmaxf(dist, 1e-9f);
  Y1[e*3+0] = vx*invd; Y1[e*3+1] = vy*invd; Y1[e*3+2] = vz*invd;
  distb[e] = dist;
  float x = fminf(fmaxf(dist * (1.0f/RMAXF), 0.0f), 1.0f);
  float x2 = x*x, x3 = x2*x;
  float cut = 1.0f - x3 * (10.0f - 15.0f*x + 6.0f*x2);
  if (dist > RMAXF) cut = 0.0f;
  float rinv = cut / fmaxf(dist, 1e-6f);
  #pragma unroll
  for (int k = 0; k < NB; k++)
    basis[e*NB + k] = sinf(freqs[k] * dist) * rinv;
}

// ---------------- node init ----------------
__global__ __launch_bounds__(256) void k_node_init(
    const int* __restrict__ species, const float* __restrict__ emb, float* __restrict__ s)
{
  int i = blockIdx.x * 256 + threadIdx.x;
  if (i >= N_NODES * C) return;
  int n = i >> 5, c = i & 31;
  s[i] = emb[species[n]*C + c];
}

// ---------------- CSR build ----------------
__global__ __launch_bounds__(256) void k_hist(const int* __restrict__ ei, int* __restrict__ counts)
{
  int e = blockIdx.x * 256 + threadIdx.x;
  if (e >= N_EDGES) return;
  atomicAdd(&counts[ei[N_EDGES + e]], 1);
}

__global__ __launch_bounds__(256) void k_scanA(const int* __restrict__ counts, int* __restrict__ bsum)
{
  __shared__ int sh[256];
  int i = blockIdx.x * 256 + threadIdx.x;
  int x = (i < N_NODES) ? counts[i] : 0;
  sh[threadIdx.x] = x;
  __syncthreads();
  for (int off = 128; off > 0; off >>= 1) {
    if (threadIdx.x < off) sh[threadIdx.x] += sh[threadIdx.x + off];
    __syncthreads();
  }
  if (threadIdx.x == 0) bsum[blockIdx.x] = sh[0];
}

__global__ void k_scanB(int* __restrict__ bsum)
{
  if (threadIdx.x == 0) {
    int acc = 0;
    for (int b = 0; b < NBLK_N; b++) { int t = bsum[b]; bsum[b] = acc; acc += t; }
  }
}

__global__ __launch_bounds__(256) void k_scanC(const int* __restrict__ counts,
                                               const int* __restrict__ bsum,
                                               int* __restrict__ row_start)
{
  __shared__ int sh[256];
  int i = blockIdx.x * 256 + threadIdx.x;
  int x = (i < N_NODES) ? counts[i] : 0;
  sh[threadIdx.x] = x;
  __syncthreads();
  for (int off = 1; off < 256; off <<= 1) {
    int y = (threadIdx.x >= off) ? sh[threadIdx.x - off] : 0;
    __syncthreads();
    sh[threadIdx.x] += y;
    __syncthreads();
  }
  if (i < N_NODES) row_start[i] = bsum[blockIdx.x] + sh[threadIdx.x] - x; // exclusive
}

__global__ __launch_bounds__(256) void k_scatter(const int* __restrict__ ei,
                                                 const int* __restrict__ row_start,
                                                 int* __restrict__ cursor,
                                                 const float* __restrict__ Y1,
                                                 const float* __restrict__ distb,
                                                 int* __restrict__ srcs,
                                                 float* __restrict__ Y1s,
                                                 float* __restrict__ dist_s)
{
  int e = blockIdx.x * 256 + threadIdx.x;
  if (e >= N_EDGES) return;
  int d = ei[N_EDGES + e];
  int p = row_start[d] + atomicAdd(&cursor[d], 1);
  srcs[p] = ei[e];
  dist_s[p] = distb[e];
  Y1s[p*3+0] = Y1[e*3+0];
  Y1s[p*3+1] = Y1[e*3+1];
  Y1s[p*3+2] = Y1[e*3+2];
}

// ---------------- radial-MLP tabulation ----------------
__global__ __launch_bounds__(256) void k_table_h(
    const float* __restrict__ freqs,
    const float* __restrict__ rW1, const float* __restrict__ rb1,
    const float* __restrict__ rW2, const float* __restrict__ rb2,
    float* __restrict__ h2tab)                 // [NL*TBL*HID]
{
  int idx = blockIdx.x * 256 + threadIdx.x;    // [NL*TBL]
  if (idx >= NL * TBL) return;
  int l = idx / TBL, i = idx - l * TBL;
  float d = (float)i * (RMAXF / (float)(TBL - 1));
  float x = fminf(fmaxf(d * (1.0f/RMAXF), 0.0f), 1.0f);
  float x2 = x*x, x3 = x2*x;
  float cut = 1.0f - x3 * (10.0f - 15.0f*x + 6.0f*x2);
  float rinv = cut / fmaxf(d, 1e-6f);
  float bas[NB];
  #pragma unroll
  for (int k = 0; k < NB; k++) bas[k] = sinf(freqs[k] * d) * rinv;

  const float* W1 = rW1 + l*NB*HID;
  const float* B1 = rb1 + l*HID;
  const float* W2 = rW2 + l*HID*HID;
  const float* B2 = rb2 + l*HID;

  float h2[HID];
  #pragma unroll
  for (int j = 0; j < HID; j++) h2[j] = B2[j];
  #pragma unroll 2
  for (int k = 0; k < HID; k++) {
    float t = B1[k];
    #pragma unroll
    for (int b = 0; b < NB; b++) t = fmaf(bas[b], W1[b*HID + k], t);
    float h1k = silu_f(t);
    const float* r = W2 + k*HID;
    #pragma unroll
    for (int j = 0; j < HID; j++) h2[j] = fmaf(h1k, r[j], h2[j]);
  }
  float* out = h2tab + (size_t)idx * HID;
  #pragma unroll
  for (int j = 0; j < HID; j++) out[j] = silu_f(h2[j]);
}

__global__ __launch_bounds__(256) void k_table_w(
    const float* __restrict__ h2tab,
    const float* __restrict__ rW3, const float* __restrict__ rb3,
    float* __restrict__ wtab)                  // [NL*TBL*128]
{
  int idx = blockIdx.x * 256 + threadIdx.x;    // [NL*TBL*16]
  if (idx >= NL * TBL * 16) return;
  int chunk = idx & 15;
  int row   = idx >> 4;                        // l*TBL + i
  int l     = row / TBL;
  const float* h2 = h2tab + (size_t)row * HID;
  const float* W3 = rW3 + l*HID*4*C + chunk*8;
  const float* B3 = rb3 + l*4*C + chunk*8;
  float a[8];
  #pragma unroll
  for (int ci = 0; ci < 8; ci++) a[ci] = B3[ci];
  #pragma unroll 4
  for (int k = 0; k < HID; k++) {
    float h = h2[k];
    #pragma unroll
    for (int ci = 0; ci < 8; ci++) a[ci] = fmaf(h, W3[k*4*C + ci], a[ci]);
  }
  float* out = wtab + (size_t)row * 128 + chunk*8;
  #pragma unroll
  for (int ci = 0; ci < 8; ci++) out[ci] = a[ci];
}

// ---------------- aggregate (table lerp) + gate + self-interaction ----------------
// r9 mapping restored: 32 lanes per node (c = lane&31), 8 nodes/block -> max wave
// residency (VGPR target <= 64 keeps 8 waves/SIMD). NO block sync / NO BN here:
// BN stats moved to k_bn_stats (streaming) so gather waves retire independently
// (r10's block-wide __syncthreads coupled every wave to the slowest node).
// Sequential 2-edge unroll (i, i+1): two independent load batches in flight.
__global__ __launch_bounds__(256) void k_agg_update(
    const float* __restrict__ tb,              // this layer's wtab [TBL][128]
    const float* __restrict__ dist_s, const float* __restrict__ Y1s,
    const int* __restrict__ srcs,
    const int* __restrict__ row_start, const int* __restrict__ counts,
    const float* __restrict__ s, const float* __restrict__ v,
    const float* __restrict__ Wss, const float* __restrict__ bss,
    const float* __restrict__ Wvv,
    float* __restrict__ s_new, float* __restrict__ v_new)
{
  int t = blockIdx.x * 256 + threadIdx.x;
  int n = t >> 5;
  int c = t & 31;

  const float SCALE = (float)(TBL - 1) / RMAXF;
  float asf = 0.0f, asg = 0.0f, av0 = 0.0f, av1 = 0.0f, av2 = 0.0f;
  int beg = row_start[n], cnt = counts[n];

  int i = 0;
  for (; i + 1 < cnt; i += 2) {
    int pA = beg + i, pB = beg + i + 1;
    float dA = dist_s[pA],  dB = dist_s[pB];
    int srcA = srcs[pA],    srcB = srcs[pB];
    float yA0 = Y1s[pA*3+0], yA1 = Y1s[pA*3+1], yA2 = Y1s[pA*3+2];
    float yB0 = Y1s[pB*3+0], yB1 = Y1s[pB*3+1], yB2 = Y1s[pB*3+2];

    float tsA = fminf(dA, RMAXF) * SCALE;
    int t0A = (int)tsA; t0A = t0A > TBL-2 ? TBL-2 : t0A;
    float frA = tsA - (float)t0A;
    float tsB = fminf(dB, RMAXF) * SCALE;
    int t0B = (int)tsB; t0B = t0B > TBL-2 ? TBL-2 : t0B;
    float frB = tsB - (float)t0B;

    const float* rA0 = tb + (size_t)t0A * 128 + c;
    const float* rA1 = rA0 + 128;
    const float* rB0 = tb + (size_t)t0B * 128 + c;
    const float* rB1 = rB0 + 128;

    float a00 = rA0[0],  a01 = rA1[0];
    float a10 = rA0[32], a11 = rA1[32];
    float a20 = rA0[64], a21 = rA1[64];
    float a30 = rA0[96], a31 = rA1[96];
    float b00 = rB0[0],  b01 = rB1[0];
    float b10 = rB0[32], b11 = rB1[32];
    float b20 = rB0[64], b21 = rB1[64];
    float b30 = rB0[96], b31 = rB1[96];

    float xsA = s[srcA*C + c];
    const float* vpA = v + (size_t)(srcA*C + c)*3;
    float xvA0 = vpA[0], xvA1 = vpA[1], xvA2 = vpA[2];
    float xsB = s[srcB*C + c];
    const float* vpB = v + (size_t)(srcB*C + c)*3;
    float xvB0 = vpB[0], xvB1 = vpB[1], xvB2 = vpB[2];

    float w1A = fmaf(frA, a01-a00, a00);
    float w2A = fmaf(frA, a11-a10, a10);
    float w3A = fmaf(frA, a21-a20, a20);
    float w4A = fmaf(frA, a31-a30, a30);
    asf = fmaf(w1A, xsA, asf);
    asg = fmaf(w2A, xvA0*yA0 + xvA1*yA1 + xvA2*yA2, asg);
    float w3xsA = w3A * xsA;
    av0 += fmaf(w3xsA, yA0, w4A*xvA0);
    av1 += fmaf(w3xsA, yA1, w4A*xvA1);
    av2 += fmaf(w3xsA, yA2, w4A*xvA2);

    float w1B = fmaf(frB, b01-b00, b00);
    float w2B = fmaf(frB, b11-b10, b10);
    float w3B = fmaf(frB, b21-b20, b20);
    float w4B = fmaf(frB, b31-b30, b30);
    asf = fmaf(w1B, xsB, asf);
    asg = fmaf(w2B, xvB0*yB0 + xvB1*yB1 + xvB2*yB2, asg);
    float w3xsB = w3B * xsB;
    av0 += fmaf(w3xsB, yB0, w4B*xvB0);
    av1 += fmaf(w3xsB, yB1, w4B*xvB1);
    av2 += fmaf(w3xsB, yB2, w4B*xvB2);
  }
  if (i < cnt) {
    int p = beg + i;
    float d  = dist_s[p];
    int src = srcs[p];
    float y0 = Y1s[p*3+0], y1 = Y1s[p*3+1], y2 = Y1s[p*3+2];
    float ts = fminf(d, RMAXF) * SCALE;
    int   t0 = (int)ts; t0 = t0 > TBL-2 ? TBL-2 : t0;
    float fr = ts - (float)t0;
    const float* r0 = tb + (size_t)t0 * 128 + c;
    const float* r1 = r0 + 128;
    float w1 = fmaf(fr, r1[0]  - r0[0],  r0[0]);
    float w2 = fmaf(fr, r1[32] - r0[32], r0[32]);
    float w3 = fmaf(fr, r1[64] - r0[64], r0[64]);
    float w4 = fmaf(fr, r1[96] - r0[96], r0[96]);
    float xs = s[src*C + c];
    const float* vp = v + (size_t)(src*C + c)*3;
    float xv0 = vp[0], xv1 = vp[1], xv2 = vp[2];
    asf = fmaf(w1, xs, asf);
    asg = fmaf(w2, xv0*y0 + xv1*y1 + xv2*y2, asg);
    float w3xs = w3 * xs;
    av0 += fmaf(w3xs, y0, w4*xv0);
    av1 += fmaf(w3xs, y1, w4*xv1);
    av2 += fmaf(w3xs, y2, w4*xv2);
  }

  float sgv  = silu_f(asf);
  float gate = sigmoid_f(asg);
  float vg0 = gate*av0, vg1 = gate*av1, vg2 = gate*av2;

  // self-interaction: 32x32 mix via lane broadcast
  float sn = bss[c];
  float vm0 = 0.0f, vm1 = 0.0f, vm2 = 0.0f;
  #pragma unroll
  for (int k = 0; k < C; k++) {
    float a  = __shfl(sgv, k, 32);
    sn = fmaf(a, Wss[k*C + c], sn);
    float wv = Wvv[k*C + c];
    vm0 = fmaf(__shfl(vg0, k, 32), wv, vm0);
    vm1 = fmaf(__shfl(vg1, k, 32), wv, vm1);
    vm2 = fmaf(__shfl(vg2, k, 32), wv, vm2);
  }

  s_new[n*C + c] = sn;
  float* vo = v_new + (size_t)(n*C + c)*3;
  vo[0] = vm0; vo[1] = vm1; vo[2] = vm2;
}

// ---------------- BN stats (streaming over s_new / v_new) ----------------
__global__ __launch_bounds__(256) void k_bn_stats(
    const float* __restrict__ s_new, const float* __restrict__ v_new,
    double* __restrict__ bn_sums)
{
  __shared__ float lacc[3*C];
  int i = blockIdx.x * 256 + threadIdx.x;      // i < N_NODES*C
  int c = i & 31;
  if (threadIdx.x < 3*C) lacc[threadIdx.x] = 0.0f;
  __syncthreads();
  float sn = s_new[i];
  const float* vp = v_new + (size_t)i*3;
  float vn2 = vp[0]*vp[0] + vp[1]*vp[1] + vp[2]*vp[2];
  atomicAdd(&lacc[c],       sn);
  atomicAdd(&lacc[C + c],   sn*sn);
  atomicAdd(&lacc[2*C + c], vn2);
  __syncthreads();
  if (threadIdx.x < 3*C) atomAddD(&bn_sums[threadIdx.x], (double)lacc[threadIdx.x]);
}

// ---------------- BN scales ----------------
__global__ void k_bn_scales(const double* __restrict__ bn_sums,
                            const float* __restrict__ gs, const float* __restrict__ gv,
                            float* __restrict__ scales)
{
  int m = threadIdx.x;
  if (m >= C) return;
  double S1 = bn_sums[m], S2 = bn_sums[C + m], VN = bn_sums[2*C + m];
  double mu  = S1 / (double)N_NODES;
  double var = S2 / (double)N_NODES - mu*mu;
  double vn2 = VN / (3.0 * (double)N_NODES);
  scales[m]       = (float)mu;
  scales[C + m]   = gs[m] / sqrtf((float)var + EPSF);
  scales[2*C + m] = gv[m] / sqrtf((float)vn2 + EPSF);
}

// ---------------- apply BN + residual ----------------
__global__ __launch_bounds__(256) void k_apply(
    const float* __restrict__ s_new, const float* __restrict__ v_new,
    const float* __restrict__ scales, const float* __restrict__ bn_bs,
    float* __restrict__ s, float* __restrict__ v)
{
  int i = blockIdx.x * 256 + threadIdx.x;
  if (i >= N_NODES * C) return;
  int c = i & 31;
  s[i] += (s_new[i] - scales[c]) * scales[C + c] + bn_bs[c];
  float vs = scales[2*C + c];
  v[(size_t)i*3+0] += v_new[(size_t)i*3+0] * vs;
  v[(size_t)i*3+1] += v_new[(size_t)i*3+1] * vs;
  v[(size_t)i*3+2] += v_new[(size_t)i*3+2] * vs;
}

// ---------------- readout ----------------
__global__ __launch_bounds__(256) void k_readout(
    const float* __restrict__ s, const int* __restrict__ species,
    const int* __restrict__ batch,
    const float* __restrict__ W_out, const float* __restrict__ b_out,
    const float* __restrict__ atom_ref, float* __restrict__ out)
{
  __shared__ float acc[NG];
  if (threadIdx.x < NG) acc[threadIdx.x] = 0.0f;
  __syncthreads();
  int n = blockIdx.x * 256 + threadIdx.x;
  if (n < N_NODES) {
    float e = b_out[0] + atom_ref[species[n]];
    #pragma unroll
    for (int c = 0; c < C; c++) e = fmaf(s[n*C + c], W_out[c], e);
    atomicAdd(&acc[batch[n]], e);
  }
  __syncthreads();
  if (threadIdx.x < NG) {
    float a = acc[threadIdx.x];
    if (a != 0.0f) atomAddF(&out[threadIdx.x], a);
  }
}

// ================= FALLBACK (atomic path, used only if ws too small) ==========
__global__ __launch_bounds__(256) void k_edge_msg_fb(
    const float* __restrict__ basis, const float* __restrict__ Y1,
    const int* __restrict__ ei,
    const float* __restrict__ s, const float* __restrict__ v,
    const float* __restrict__ rW1, const float* __restrict__ rb1,
    const float* __restrict__ rW2, const float* __restrict__ rb2,
    const float* __restrict__ rW3, const float* __restrict__ rb3,
    float* __restrict__ agg_sf, float* __restrict__ agg_sg, float* __restrict__ agg_v)
{
  int e = blockIdx.x * 256 + threadIdx.x;
  if (e >= N_EDGES) return;
  int src = ei[e], dst = ei[N_EDGES + e];
  const float4 b0 = *(const float4*)(basis + (size_t)e*NB);
  const float4 b1 = *(const float4*)(basis + (size_t)e*NB + 4);
  float bas[NB] = {b0.x, b0.y, b0.z, b0.w, b1.x, b1.y, b1.z, b1.w};
  float h2[HID];
  #pragma unroll
  for (int j = 0; j < HID; j++) h2[j] = rb2[j];
  #pragma unroll 2
  for (int k = 0; k < HID; k++) {
    float t = rb1[k];
    #pragma unroll
    for (int b = 0; b < NB; b++) t = fmaf(bas[b], rW1[b*HID + k], t);
    float h1k = silu_f(t);
    const float* r = rW2 + k*HID;
    #pragma unroll
    for (int j = 0; j < HID; j++) h2[j] = fmaf(h1k, r[j], h2[j]);
  }
  #pragma unroll
  for (int j = 0; j < HID; j++) h2[j] = silu_f(h2[j]);
  float y0 = Y1[e*3+0], y1 = Y1[e*3+1], y2 = Y1[e*3+2];
  #pragma unroll 1
  for (int cb = 0; cb < 16; cb++) {
    float a[8];
    #pragma unroll
    for (int ci = 0; ci < 8; ci++) a[ci] = rb3[cb*8 + ci];
    #pragma unroll
    for (int k = 0; k < HID; k++) {
      float h = h2[k];
      #pragma unroll
      for (int ci = 0; ci < 8; ci++) a[ci] = fmaf(h, rW3[k*4*C + cb*8 + ci], a[ci]);
    }
    #pragma unroll
    for (int ci = 0; ci < 8; ci++) {
      int o = cb*8 + ci;
      int path = o >> 5;
      int c = o & 31;
      float xs = s[src*C + c];
      const float* vp = v + (size_t)(src*C + c)*3;
      float xv0 = vp[0], xv1 = vp[1], xv2 = vp[2];
      if (path == 0) {
        atomAddF(&agg_sf[dst*C + c], a[ci] * xs);
      } else if (path == 1) {
        atomAddF(&agg_sg[dst*C + c], a[ci] * (xv0*y0 + xv1*y1 + xv2*y2));
      } else if (path == 2) {
        float w3xs = a[ci] * xs;
        float* ap = agg_v + (size_t)(dst*C + c)*3;
        atomAddF(ap+0, w3xs*y0); atomAddF(ap+1, w3xs*y1); atomAddF(ap+2, w3xs*y2);
      } else {
        float* ap = agg_v + (size_t)(dst*C + c)*3;
        atomAddF(ap+0, a[ci]*xv0); atomAddF(ap+1, a[ci]*xv1); atomAddF(ap+2, a[ci]*xv2);
      }
    }
  }
}

__global__ __launch_bounds__(256) void k_node_update_fb(
    const float* __restrict__ agg_sf, const float* __restrict__ agg_sg,
    const float* __restrict__ agg_v,
    const float* __restrict__ Wss, const float* __restrict__ bss,
    const float* __restrict__ Wvv,
    float* __restrict__ s_new, float* __restrict__ v_new,
    double* __restrict__ bn_sums)
{
  __shared__ float lacc[3*C];
  int t = blockIdx.x * 256 + threadIdx.x;
  int n = t >> 5;
  int c = t & 31;
  if (threadIdx.x < 3*C) lacc[threadIdx.x] = 0.0f;
  __syncthreads();
  float asf = agg_sf[n*C + c];
  float asg = agg_sg[n*C + c];
  const float* ap = agg_v + (size_t)(n*C + c)*3;
  float av0 = ap[0], av1 = ap[1], av2 = ap[2];
  float sgv = silu_f(asf);
  float gate = sigmoid_f(asg);
  float vg0 = gate*av0, vg1 = gate*av1, vg2 = gate*av2;
  float sn = bss[c];
  float vm0 = 0.0f, vm1 = 0.0f, vm2 = 0.0f;
  #pragma unroll
  for (int k = 0; k < C; k++) {
    float a  = __shfl(sgv, k, 32);
    sn = fmaf(a, Wss[k*C + c], sn);
    float wv = Wvv[k*C + c];
    vm0 = fmaf(__shfl(vg0, k, 32), wv, vm0);
    vm1 = fmaf(__shfl(vg1, k, 32), wv, vm1);
    vm2 = fmaf(__shfl(vg2, k, 32), wv, vm2);
  }
  s_new[n*C + c] = sn;
  float* vo = v_new + (size_t)(n*C + c)*3;
  vo[0] = vm0; vo[1] = vm1; vo[2] = vm2;
  float vn2 = vm0*vm0 + vm1*vm1 + vm2*vm2;
  atomicAdd(&lacc[c], sn);
  atomicAdd(&lacc[C + c], sn*sn);
  atomicAdd(&lacc[2*C + c], vn2);
  __syncthreads();
  if (threadIdx.x < 3*C) atomAddD(&bn_sums[threadIdx.x], (double)lacc[threadIdx.x]);
}

extern "C" void kernel_launch(void* const* d_in, const int* in_sizes, int n_in,
                              void* d_out, int out_size, void* d_ws, size_t ws_size,
                              hipStream_t stream)
{
  const int*   species  = (const int*)  d_in[0];
  const float* pos      = (const float*)d_in[1];
  const int*   ei       = (const int*)  d_in[2];
  const int*   batch    = (const int*)  d_in[3];
  const float* emb      = (const float*)d_in[4];
  const float* freqs    = (const float*)d_in[5];
  const float* rW1      = (const float*)d_in[6];
  const float* rb1      = (const float*)d_in[7];
  const float* rW2      = (const float*)d_in[8];
  const float* rb2      = (const float*)d_in[9];
  const float* rW3      = (const float*)d_in[10];
  const float* rb3      = (const float*)d_in[11];
  const float* Wss      = (const float*)d_in[12];
  const float* bss      = (const float*)d_in[13];
  const float* Wvv      = (const float*)d_in[14];
  const float* bn_gs    = (const float*)d_in[15];
  const float* bn_bs    = (const float*)d_in[16];
  const float* bn_gv    = (const float*)d_in[17];
  const float* W_out    = (const float*)d_in[18];
  const float* b_out    = (const float*)d_in[19];
  const float* atom_ref = (const float*)d_in[20];

  float* ws = (float*)d_ws;
  size_t off = 0;
  float* basis  = ws + off; off += (size_t)N_EDGES * NB;     // fb path only
  float* Y1     = ws + off; off += (size_t)N_EDGES * 3;
  float* distb  = ws + off; off += (size_t)N_EDGES;
  float* s      = ws + off; off += (size_t)N_NODES * C;
  float* v      = ws + off; off += (size_t)N_NODES * C * 3;
  float* s_new  = ws + off; off += (size_t)N_NODES * C;
  float* v_new  = ws + off; off += (size_t)N_NODES * C * 3;
  double* bn_sums = (double*)(ws + off); off += 192;
  float* scales = ws + off; off += 96;

  // --- region A (sorted + table path) ---
  size_t ra = off;
  float* Y1s      = ws + ra;            ra += (size_t)N_EDGES * 3;
  float* dist_s   = ws + ra;            ra += (size_t)N_EDGES;
  int*   srcs     = (int*)(ws + ra);    ra += N_EDGES;
  int*   counts   = (int*)(ws + ra);    ra += N_NODES;
  int*   row_start= (int*)(ws + ra);    ra += N_NODES;
  int*   cursor   = (int*)(ws + ra);    ra += N_NODES;
  int*   bsum     = (int*)(ws + ra);    ra += 256;
  float* h2tab    = ws + ra;            ra += (size_t)NL * TBL * HID;
  float* wtab     = ws + ra;            ra += (size_t)NL * TBL * 128;
  size_t req_sorted = ra * 4;

  // --- region B (fallback atomic path, aliases region A) ---
  size_t rb = off;
  float* agg_sf = ws + rb; rb += (size_t)N_NODES * C;
  float* agg_sg = ws + rb; rb += (size_t)N_NODES * C;
  float* agg_v  = ws + rb; rb += (size_t)N_NODES * C * 3;

  dim3 b256(256);
  const int gE  = (N_EDGES + 255) / 256;
  const int gNC = (N_NODES * C + 255) / 256;
  const int gN  = (N_NODES + 255) / 256;

  hipMemsetAsync(v, 0, (size_t)N_NODES * C * 3 * sizeof(float), stream);
  k_edge_geom<<<gE, b256, 0, stream>>>(pos, ei, freqs, basis, Y1, distb);
  k_node_init<<<gNC, b256, 0, stream>>>(species, emb, s);

  if (ws_size >= req_sorted) {
    hipMemsetAsync(counts, 0, N_NODES * sizeof(int), stream);
    hipMemsetAsync(cursor, 0, N_NODES * sizeof(int), stream);
    k_hist<<<gE, b256, 0, stream>>>(ei, counts);
    k_scanA<<<NBLK_N, b256, 0, stream>>>(counts, bsum);
    k_scanB<<<1, 64, 0, stream>>>(bsum);
    k_scanC<<<NBLK_N, b256, 0, stream>>>(counts, bsum, row_start);
    k_scatter<<<gE, b256, 0, stream>>>(ei, row_start, cursor, Y1, distb,
                                       srcs, Y1s, dist_s);
    k_table_h<<<(NL*TBL)/256, b256, 0, stream>>>(freqs, rW1, rb1, rW2, rb2, h2tab);
    k_table_w<<<(NL*TBL*16)/256, b256, 0, stream>>>(h2tab, rW3, rb3, wtab);

    for (int l = 0; l < NL; l++) {
      hipMemsetAsync(bn_sums, 0, 96 * sizeof(double), stream);
      k_agg_update<<<(N_NODES*C)/256, b256, 0, stream>>>(
          wtab + (size_t)l * TBL * 128, dist_s, Y1s, srcs,
          row_start, counts, s, v, Wss + l*C*C, bss + l*C, Wvv + l*C*C,
          s_new, v_new);
      k_bn_stats<<<(N_NODES*C)/256, b256, 0, stream>>>(s_new, v_new, bn_sums);
      k_bn_scales<<<1, 64, 0, stream>>>(bn_sums, bn_gs + l*C, bn_gv + l*C, scales);
      k_apply<<<gNC, b256, 0, stream>>>(s_new, v_new, scales, bn_bs + l*C, s, v);
    }
  } else {
    for (int l = 0; l < NL; l++) {
      hipMemsetAsync(agg_sf, 0, (size_t)N_NODES * 5 * C * sizeof(float), stream);
      hipMemsetAsync(bn_sums, 0, 96 * sizeof(double), stream);
      k_edge_msg_fb<<<gE, b256, 0, stream>>>(basis, Y1, ei, s, v,
          rW1 + l*NB*HID, rb1 + l*HID, rW2 + l*HID*HID, rb2 + l*HID,
          rW3 + l*HID*4*C, rb3 + l*4*C, agg_sf, agg_sg, agg_v);
      k_node_update_fb<<<(N_NODES*C)/256, b256, 0, stream>>>(agg_sf, agg_sg, agg_v,
          Wss + l*C*C, bss + l*C, Wvv + l*C*C, s_new, v_new, bn_sums);
      k_bn_scales<<<1, 64, 0, stream>>>(bn_sums, bn_gs + l*C, bn_gv + l*C, scales);
      k_apply<<<gNC, b256, 0, stream>>>(s_new, v_new, scales, bn_bs + l*C, s, v);
    }
  }

  hipMemsetAsync(d_out, 0, NG * sizeof(float), stream);
  k_readout<<<gN, b256, 0, stream>>>(s, species, batch, W_out, b_out, atom_ref, (float*)d_out);
}

// Round 12
// 337.732 us; speedup vs baseline: 2.2331x; 1.7097x over previous
//
#include <hip/hip_runtime.h>
#include <math.h>

#define N_NODES 50000
#define N_EDGES 400000
#define C 32
#define NB 8
#define HID 64
#define NL 2
#define NG 64
#define RMAXF 5.0f
#define EPSF 1e-5f
#define TBL 4096
#define BN_BLOCKS 512
#define NBLK_N ((N_NODES + 255) / 256)   // 196

__device__ __forceinline__ float silu_f(float x) { return x / (1.0f + __expf(-x)); }
__device__ __forceinline__ float sigmoid_f(float x) { return 1.0f / (1.0f + __expf(-x)); }
__device__ __forceinline__ void atomAddF(float* p, float val) {
  __hip_atomic_fetch_add(p, val, __ATOMIC_RELAXED, __HIP_MEMORY_SCOPE_AGENT);
}
__device__ __forceinline__ void atomAddD(double* p, double val) {
  __hip_atomic_fetch_add(p, val, __ATOMIC_RELAXED, __HIP_MEMORY_SCOPE_AGENT);
}

// ---------------- edge geometry ----------------
__global__ __launch_bounds__(256) void k_edge_geom(
    const float* __restrict__ pos, const int* __restrict__ ei,
    const float* __restrict__ freqs,
    float* __restrict__ basis, float* __restrict__ Y1, float* __restrict__ distb)
{
  int e = blockIdx.x * 256 + threadIdx.x;
  if (e >= N_EDGES) return;
  int s = ei[e], d = ei[N_EDGES + e];
  float vx = pos[d*3+0] - pos[s*3+0];
  float vy = pos[d*3+1] - pos[s*3+1];
  float vz = pos[d*3+2] - pos[s*3+2];
  float dist = sqrtf(vx*vx + vy*vy + vz*vz);
  float invd = 1.0f / fmaxf(dist, 1e-9f);
  Y1[e*3+0] = vx*invd; Y1[e*3+1] = vy*invd; Y1[e*3+2] = vz*invd;
  distb[e] = dist;
  float x = fminf(fmaxf(dist * (1.0f/RMAXF), 0.0f), 1.0f);
  float x2 = x*x, x3 = x2*x;
  float cut = 1.0f - x3 * (10.0f - 15.0f*x + 6.0f*x2);
  if (dist > RMAXF) cut = 0.0f;
  float rinv = cut / fmaxf(dist, 1e-6f);
  #pragma unroll
  for (int k = 0; k < NB; k++)
    basis[e*NB + k] = sinf(freqs[k] * dist) * rinv;
}

// ---------------- node init ----------------
__global__ __launch_bounds__(256) void k_node_init(
    const int* __restrict__ species, const float* __restrict__ emb, float* __restrict__ s)
{
  int i = blockIdx.x * 256 + threadIdx.x;
  if (i >= N_NODES * C) return;
  int n = i >> 5, c = i & 31;
  s[i] = emb[species[n]*C + c];
}

// ---------------- CSR build ----------------
__global__ __launch_bounds__(256) void k_hist(const int* __restrict__ ei, int* __restrict__ counts)
{
  int e = blockIdx.x * 256 + threadIdx.x;
  if (e >= N_EDGES) return;
  atomicAdd(&counts[ei[N_EDGES + e]], 1);
}

__global__ __launch_bounds__(256) void k_scanA(const int* __restrict__ counts, int* __restrict__ bsum)
{
  __shared__ int sh[256];
  int i = blockIdx.x * 256 + threadIdx.x;
  int x = (i < N_NODES) ? counts[i] : 0;
  sh[threadIdx.x] = x;
  __syncthreads();
  for (int off = 128; off > 0; off >>= 1) {
    if (threadIdx.x < off) sh[threadIdx.x] += sh[threadIdx.x + off];
    __syncthreads();
  }
  if (threadIdx.x == 0) bsum[blockIdx.x] = sh[0];
}

__global__ void k_scanB(int* __restrict__ bsum)
{
  if (threadIdx.x == 0) {
    int acc = 0;
    for (int b = 0; b < NBLK_N; b++) { int t = bsum[b]; bsum[b] = acc; acc += t; }
  }
}

__global__ __launch_bounds__(256) void k_scanC(const int* __restrict__ counts,
                                               const int* __restrict__ bsum,
                                               int* __restrict__ row_start)
{
  __shared__ int sh[256];
  int i = blockIdx.x * 256 + threadIdx.x;
  int x = (i < N_NODES) ? counts[i] : 0;
  sh[threadIdx.x] = x;
  __syncthreads();
  for (int off = 1; off < 256; off <<= 1) {
    int y = (threadIdx.x >= off) ? sh[threadIdx.x - off] : 0;
    __syncthreads();
    sh[threadIdx.x] += y;
    __syncthreads();
  }
  if (i < N_NODES) row_start[i] = bsum[blockIdx.x] + sh[threadIdx.x] - x; // exclusive
}

__global__ __launch_bounds__(256) void k_scatter(const int* __restrict__ ei,
                                                 const int* __restrict__ row_start,
                                                 int* __restrict__ cursor,
                                                 const float* __restrict__ Y1,
                                                 const float* __restrict__ distb,
                                                 int* __restrict__ srcs,
                                                 float* __restrict__ Y1s,
                                                 float* __restrict__ dist_s)
{
  int e = blockIdx.x * 256 + threadIdx.x;
  if (e >= N_EDGES) return;
  int d = ei[N_EDGES + e];
  int p = row_start[d] + atomicAdd(&cursor[d], 1);
  srcs[p] = ei[e];
  dist_s[p] = distb[e];
  Y1s[p*3+0] = Y1[e*3+0];
  Y1s[p*3+1] = Y1[e*3+1];
  Y1s[p*3+2] = Y1[e*3+2];
}

// ---------------- radial-MLP tabulation ----------------
__global__ __launch_bounds__(256) void k_table_h(
    const float* __restrict__ freqs,
    const float* __restrict__ rW1, const float* __restrict__ rb1,
    const float* __restrict__ rW2, const float* __restrict__ rb2,
    float* __restrict__ h2tab)                 // [NL*TBL*HID]
{
  int idx = blockIdx.x * 256 + threadIdx.x;    // [NL*TBL]
  if (idx >= NL * TBL) return;
  int l = idx / TBL, i = idx - l * TBL;
  float d = (float)i * (RMAXF / (float)(TBL - 1));
  float x = fminf(fmaxf(d * (1.0f/RMAXF), 0.0f), 1.0f);
  float x2 = x*x, x3 = x2*x;
  float cut = 1.0f - x3 * (10.0f - 15.0f*x + 6.0f*x2);
  float rinv = cut / fmaxf(d, 1e-6f);
  float bas[NB];
  #pragma unroll
  for (int k = 0; k < NB; k++) bas[k] = sinf(freqs[k] * d) * rinv;

  const float* W1 = rW1 + l*NB*HID;
  const float* B1 = rb1 + l*HID;
  const float* W2 = rW2 + l*HID*HID;
  const float* B2 = rb2 + l*HID;

  float h2[HID];
  #pragma unroll
  for (int j = 0; j < HID; j++) h2[j] = B2[j];
  #pragma unroll 2
  for (int k = 0; k < HID; k++) {
    float t = B1[k];
    #pragma unroll
    for (int b = 0; b < NB; b++) t = fmaf(bas[b], W1[b*HID + k], t);
    float h1k = silu_f(t);
    const float* r = W2 + k*HID;
    #pragma unroll
    for (int j = 0; j < HID; j++) h2[j] = fmaf(h1k, r[j], h2[j]);
  }
  float* out = h2tab + (size_t)idx * HID;
  #pragma unroll
  for (int j = 0; j < HID; j++) out[j] = silu_f(h2[j]);
}

__global__ __launch_bounds__(256) void k_table_w(
    const float* __restrict__ h2tab,
    const float* __restrict__ rW3, const float* __restrict__ rb3,
    float* __restrict__ wtab)                  // [NL*TBL*128]
{
  int idx = blockIdx.x * 256 + threadIdx.x;    // [NL*TBL*16]
  if (idx >= NL * TBL * 16) return;
  int chunk = idx & 15;
  int row   = idx >> 4;                        // l*TBL + i
  int l     = row / TBL;
  const float* h2 = h2tab + (size_t)row * HID;
  const float* W3 = rW3 + l*HID*4*C + chunk*8;
  const float* B3 = rb3 + l*4*C + chunk*8;
  float a[8];
  #pragma unroll
  for (int ci = 0; ci < 8; ci++) a[ci] = B3[ci];
  #pragma unroll 4
  for (int k = 0; k < HID; k++) {
    float h = h2[k];
    #pragma unroll
    for (int ci = 0; ci < 8; ci++) a[ci] = fmaf(h, W3[k*4*C + ci], a[ci]);
  }
  float* out = wtab + (size_t)row * 128 + chunk*8;
  #pragma unroll
  for (int ci = 0; ci < 8; ci++) out[ci] = a[ci];
}

// ---------------- aggregate (table lerp) + gate + self-interaction ----------------
// 32 lanes per node, no block sync, no atomics (BN stats in k_bn_stats).
// Sequential 2-edge unroll: two independent load batches in flight.
__global__ __launch_bounds__(256) void k_agg_update(
    const float* __restrict__ tb,              // this layer's wtab [TBL][128]
    const float* __restrict__ dist_s, const float* __restrict__ Y1s,
    const int* __restrict__ srcs,
    const int* __restrict__ row_start, const int* __restrict__ counts,
    const float* __restrict__ s, const float* __restrict__ v,
    const float* __restrict__ Wss, const float* __restrict__ bss,
    const float* __restrict__ Wvv,
    float* __restrict__ s_new, float* __restrict__ v_new)
{
  int t = blockIdx.x * 256 + threadIdx.x;
  int n = t >> 5;
  int c = t & 31;

  const float SCALE = (float)(TBL - 1) / RMAXF;
  float asf = 0.0f, asg = 0.0f, av0 = 0.0f, av1 = 0.0f, av2 = 0.0f;
  int beg = row_start[n], cnt = counts[n];

  int i = 0;
  for (; i + 1 < cnt; i += 2) {
    int pA = beg + i, pB = beg + i + 1;
    float dA = dist_s[pA],  dB = dist_s[pB];
    int srcA = srcs[pA],    srcB = srcs[pB];
    float yA0 = Y1s[pA*3+0], yA1 = Y1s[pA*3+1], yA2 = Y1s[pA*3+2];
    float yB0 = Y1s[pB*3+0], yB1 = Y1s[pB*3+1], yB2 = Y1s[pB*3+2];

    float tsA = fminf(dA, RMAXF) * SCALE;
    int t0A = (int)tsA; t0A = t0A > TBL-2 ? TBL-2 : t0A;
    float frA = tsA - (float)t0A;
    float tsB = fminf(dB, RMAXF) * SCALE;
    int t0B = (int)tsB; t0B = t0B > TBL-2 ? TBL-2 : t0B;
    float frB = tsB - (float)t0B;

    const float* rA0 = tb + (size_t)t0A * 128 + c;
    const float* rA1 = rA0 + 128;
    const float* rB0 = tb + (size_t)t0B * 128 + c;
    const float* rB1 = rB0 + 128;

    float a00 = rA0[0],  a01 = rA1[0];
    float a10 = rA0[32], a11 = rA1[32];
    float a20 = rA0[64], a21 = rA1[64];
    float a30 = rA0[96], a31 = rA1[96];
    float b00 = rB0[0],  b01 = rB1[0];
    float b10 = rB0[32], b11 = rB1[32];
    float b20 = rB0[64], b21 = rB1[64];
    float b30 = rB0[96], b31 = rB1[96];

    float xsA = s[srcA*C + c];
    const float* vpA = v + (size_t)(srcA*C + c)*3;
    float xvA0 = vpA[0], xvA1 = vpA[1], xvA2 = vpA[2];
    float xsB = s[srcB*C + c];
    const float* vpB = v + (size_t)(srcB*C + c)*3;
    float xvB0 = vpB[0], xvB1 = vpB[1], xvB2 = vpB[2];

    float w1A = fmaf(frA, a01-a00, a00);
    float w2A = fmaf(frA, a11-a10, a10);
    float w3A = fmaf(frA, a21-a20, a20);
    float w4A = fmaf(frA, a31-a30, a30);
    asf = fmaf(w1A, xsA, asf);
    asg = fmaf(w2A, xvA0*yA0 + xvA1*yA1 + xvA2*yA2, asg);
    float w3xsA = w3A * xsA;
    av0 += fmaf(w3xsA, yA0, w4A*xvA0);
    av1 += fmaf(w3xsA, yA1, w4A*xvA1);
    av2 += fmaf(w3xsA, yA2, w4A*xvA2);

    float w1B = fmaf(frB, b01-b00, b00);
    float w2B = fmaf(frB, b11-b10, b10);
    float w3B = fmaf(frB, b21-b20, b20);
    float w4B = fmaf(frB, b31-b30, b30);
    asf = fmaf(w1B, xsB, asf);
    asg = fmaf(w2B, xvB0*yB0 + xvB1*yB1 + xvB2*yB2, asg);
    float w3xsB = w3B * xsB;
    av0 += fmaf(w3xsB, yB0, w4B*xvB0);
    av1 += fmaf(w3xsB, yB1, w4B*xvB1);
    av2 += fmaf(w3xsB, yB2, w4B*xvB2);
  }
  if (i < cnt) {
    int p = beg + i;
    float d  = dist_s[p];
    int src = srcs[p];
    float y0 = Y1s[p*3+0], y1 = Y1s[p*3+1], y2 = Y1s[p*3+2];
    float ts = fminf(d, RMAXF) * SCALE;
    int   t0 = (int)ts; t0 = t0 > TBL-2 ? TBL-2 : t0;
    float fr = ts - (float)t0;
    const float* r0 = tb + (size_t)t0 * 128 + c;
    const float* r1 = r0 + 128;
    float w1 = fmaf(fr, r1[0]  - r0[0],  r0[0]);
    float w2 = fmaf(fr, r1[32] - r0[32], r0[32]);
    float w3 = fmaf(fr, r1[64] - r0[64], r0[64]);
    float w4 = fmaf(fr, r1[96] - r0[96], r0[96]);
    float xs = s[src*C + c];
    const float* vp = v + (size_t)(src*C + c)*3;
    float xv0 = vp[0], xv1 = vp[1], xv2 = vp[2];
    asf = fmaf(w1, xs, asf);
    asg = fmaf(w2, xv0*y0 + xv1*y1 + xv2*y2, asg);
    float w3xs = w3 * xs;
    av0 += fmaf(w3xs, y0, w4*xv0);
    av1 += fmaf(w3xs, y1, w4*xv1);
    av2 += fmaf(w3xs, y2, w4*xv2);
  }

  float sgv  = silu_f(asf);
  float gate = sigmoid_f(asg);
  float vg0 = gate*av0, vg1 = gate*av1, vg2 = gate*av2;

  // self-interaction: 32x32 mix via lane broadcast
  float sn = bss[c];
  float vm0 = 0.0f, vm1 = 0.0f, vm2 = 0.0f;
  #pragma unroll
  for (int k = 0; k < C; k++) {
    float a  = __shfl(sgv, k, 32);
    sn = fmaf(a, Wss[k*C + c], sn);
    float wv = Wvv[k*C + c];
    vm0 = fmaf(__shfl(vg0, k, 32), wv, vm0);
    vm1 = fmaf(__shfl(vg1, k, 32), wv, vm1);
    vm2 = fmaf(__shfl(vg2, k, 32), wv, vm2);
  }

  s_new[n*C + c] = sn;
  float* vo = v_new + (size_t)(n*C + c)*3;
  vo[0] = vm0; vo[1] = vm1; vo[2] = vm2;
}

// ---------------- BN stats (grid-stride; few blocks -> few same-address atomics) --
// r11 lesson: 6250 blocks x 96 doubles to the SAME 96 addresses = 6250-deep
// serialized RMW chain per address (~140us at ~22ns each). Grid-stride with
// BN_BLOCKS=512: stride is a multiple of 32 so each thread's channel c is
// loop-invariant -> register accumulation, then 512 atomics/address (~12us).
__global__ __launch_bounds__(256) void k_bn_stats(
    const float* __restrict__ s_new, const float* __restrict__ v_new,
    double* __restrict__ bn_sums)
{
  __shared__ float lacc[3*C];
  if (threadIdx.x < 3*C) lacc[threadIdx.x] = 0.0f;
  __syncthreads();
  int c = threadIdx.x & 31;
  float r1 = 0.0f, r2 = 0.0f, r3 = 0.0f;
  const int NC = N_NODES * C;
  for (int i = blockIdx.x * 256 + threadIdx.x; i < NC; i += BN_BLOCKS * 256) {
    float sn = s_new[i];
    const float* vp = v_new + (size_t)i * 3;
    r1 += sn;
    r2 += sn * sn;
    r3 += vp[0]*vp[0] + vp[1]*vp[1] + vp[2]*vp[2];
  }
  atomicAdd(&lacc[c],       r1);
  atomicAdd(&lacc[C + c],   r2);
  atomicAdd(&lacc[2*C + c], r3);
  __syncthreads();
  if (threadIdx.x < 3*C) atomAddD(&bn_sums[threadIdx.x], (double)lacc[threadIdx.x]);
}

// ---------------- BN scales ----------------
__global__ void k_bn_scales(const double* __restrict__ bn_sums,
                            const float* __restrict__ gs, const float* __restrict__ gv,
                            float* __restrict__ scales)
{
  int m = threadIdx.x;
  if (m >= C) return;
  double S1 = bn_sums[m], S2 = bn_sums[C + m], VN = bn_sums[2*C + m];
  double mu  = S1 / (double)N_NODES;
  double var = S2 / (double)N_NODES - mu*mu;
  double vn2 = VN / (3.0 * (double)N_NODES);
  scales[m]       = (float)mu;
  scales[C + m]   = gs[m] / sqrtf((float)var + EPSF);
  scales[2*C + m] = gv[m] / sqrtf((float)vn2 + EPSF);
}

// ---------------- apply BN + residual ----------------
__global__ __launch_bounds__(256) void k_apply(
    const float* __restrict__ s_new, const float* __restrict__ v_new,
    const float* __restrict__ scales, const float* __restrict__ bn_bs,
    float* __restrict__ s, float* __restrict__ v)
{
  int i = blockIdx.x * 256 + threadIdx.x;
  if (i >= N_NODES * C) return;
  int c = i & 31;
  s[i] += (s_new[i] - scales[c]) * scales[C + c] + bn_bs[c];
  float vs = scales[2*C + c];
  v[(size_t)i*3+0] += v_new[(size_t)i*3+0] * vs;
  v[(size_t)i*3+1] += v_new[(size_t)i*3+1] * vs;
  v[(size_t)i*3+2] += v_new[(size_t)i*3+2] * vs;
}

// ---------------- readout ----------------
__global__ __launch_bounds__(256) void k_readout(
    const float* __restrict__ s, const int* __restrict__ species,
    const int* __restrict__ batch,
    const float* __restrict__ W_out, const float* __restrict__ b_out,
    const float* __restrict__ atom_ref, float* __restrict__ out)
{
  __shared__ float acc[NG];
  if (threadIdx.x < NG) acc[threadIdx.x] = 0.0f;
  __syncthreads();
  int n = blockIdx.x * 256 + threadIdx.x;
  if (n < N_NODES) {
    float e = b_out[0] + atom_ref[species[n]];
    #pragma unroll
    for (int c = 0; c < C; c++) e = fmaf(s[n*C + c], W_out[c], e);
    atomicAdd(&acc[batch[n]], e);
  }
  __syncthreads();
  if (threadIdx.x < NG) {
    float a = acc[threadIdx.x];
    if (a != 0.0f) atomAddF(&out[threadIdx.x], a);
  }
}

// ================= FALLBACK (atomic path, used only if ws too small) ==========
__global__ __launch_bounds__(256) void k_edge_msg_fb(
    const float* __restrict__ basis, const float* __restrict__ Y1,
    const int* __restrict__ ei,
    const float* __restrict__ s, const float* __restrict__ v,
    const float* __restrict__ rW1, const float* __restrict__ rb1,
    const float* __restrict__ rW2, const float* __restrict__ rb2,
    const float* __restrict__ rW3, const float* __restrict__ rb3,
    float* __restrict__ agg_sf, float* __restrict__ agg_sg, float* __restrict__ agg_v)
{
  int e = blockIdx.x * 256 + threadIdx.x;
  if (e >= N_EDGES) return;
  int src = ei[e], dst = ei[N_EDGES + e];
  const float4 b0 = *(const float4*)(basis + (size_t)e*NB);
  const float4 b1 = *(const float4*)(basis + (size_t)e*NB + 4);
  float bas[NB] = {b0.x, b0.y, b0.z, b0.w, b1.x, b1.y, b1.z, b1.w};
  float h2[HID];
  #pragma unroll
  for (int j = 0; j < HID; j++) h2[j] = rb2[j];
  #pragma unroll 2
  for (int k = 0; k < HID; k++) {
    float t = rb1[k];
    #pragma unroll
    for (int b = 0; b < NB; b++) t = fmaf(bas[b], rW1[b*HID + k], t);
    float h1k = silu_f(t);
    const float* r = rW2 + k*HID;
    #pragma unroll
    for (int j = 0; j < HID; j++) h2[j] = fmaf(h1k, r[j], h2[j]);
  }
  #pragma unroll
  for (int j = 0; j < HID; j++) h2[j] = silu_f(h2[j]);
  float y0 = Y1[e*3+0], y1 = Y1[e*3+1], y2 = Y1[e*3+2];
  #pragma unroll 1
  for (int cb = 0; cb < 16; cb++) {
    float a[8];
    #pragma unroll
    for (int ci = 0; ci < 8; ci++) a[ci] = rb3[cb*8 + ci];
    #pragma unroll
    for (int k = 0; k < HID; k++) {
      float h = h2[k];
      #pragma unroll
      for (int ci = 0; ci < 8; ci++) a[ci] = fmaf(h, rW3[k*4*C + cb*8 + ci], a[ci]);
    }
    #pragma unroll
    for (int ci = 0; ci < 8; ci++) {
      int o = cb*8 + ci;
      int path = o >> 5;
      int c = o & 31;
      float xs = s[src*C + c];
      const float* vp = v + (size_t)(src*C + c)*3;
      float xv0 = vp[0], xv1 = vp[1], xv2 = vp[2];
      if (path == 0) {
        atomAddF(&agg_sf[dst*C + c], a[ci] * xs);
      } else if (path == 1) {
        atomAddF(&agg_sg[dst*C + c], a[ci] * (xv0*y0 + xv1*y1 + xv2*y2));
      } else if (path == 2) {
        float w3xs = a[ci] * xs;
        float* ap = agg_v + (size_t)(dst*C + c)*3;
        atomAddF(ap+0, w3xs*y0); atomAddF(ap+1, w3xs*y1); atomAddF(ap+2, w3xs*y2);
      } else {
        float* ap = agg_v + (size_t)(dst*C + c)*3;
        atomAddF(ap+0, a[ci]*xv0); atomAddF(ap+1, a[ci]*xv1); atomAddF(ap+2, a[ci]*xv2);
      }
    }
  }
}

__global__ __launch_bounds__(256) void k_node_update_fb(
    const float* __restrict__ agg_sf, const float* __restrict__ agg_sg,
    const float* __restrict__ agg_v,
    const float* __restrict__ Wss, const float* __restrict__ bss,
    const float* __restrict__ Wvv,
    float* __restrict__ s_new, float* __restrict__ v_new,
    double* __restrict__ bn_sums)
{
  __shared__ float lacc[3*C];
  int t = blockIdx.x * 256 + threadIdx.x;
  int n = t >> 5;
  int c = t & 31;
  if (threadIdx.x < 3*C) lacc[threadIdx.x] = 0.0f;
  __syncthreads();
  float asf = agg_sf[n*C + c];
  float asg = agg_sg[n*C + c];
  const float* ap = agg_v + (size_t)(n*C + c)*3;
  float av0 = ap[0], av1 = ap[1], av2 = ap[2];
  float sgv = silu_f(asf);
  float gate = sigmoid_f(asg);
  float vg0 = gate*av0, vg1 = gate*av1, vg2 = gate*av2;
  float sn = bss[c];
  float vm0 = 0.0f, vm1 = 0.0f, vm2 = 0.0f;
  #pragma unroll
  for (int k = 0; k < C; k++) {
    float a  = __shfl(sgv, k, 32);
    sn = fmaf(a, Wss[k*C + c], sn);
    float wv = Wvv[k*C + c];
    vm0 = fmaf(__shfl(vg0, k, 32), wv, vm0);
    vm1 = fmaf(__shfl(vg1, k, 32), wv, vm1);
    vm2 = fmaf(__shfl(vg2, k, 32), wv, vm2);
  }
  s_new[n*C + c] = sn;
  float* vo = v_new + (size_t)(n*C + c)*3;
  vo[0] = vm0; vo[1] = vm1; vo[2] = vm2;
  float vn2 = vm0*vm0 + vm1*vm1 + vm2*vm2;
  atomicAdd(&lacc[c], sn);
  atomicAdd(&lacc[C + c], sn*sn);
  atomicAdd(&lacc[2*C + c], vn2);
  __syncthreads();
  if (threadIdx.x < 3*C) atomAddD(&bn_sums[threadIdx.x], (double)lacc[threadIdx.x]);
}

extern "C" void kernel_launch(void* const* d_in, const int* in_sizes, int n_in,
                              void* d_out, int out_size, void* d_ws, size_t ws_size,
                              hipStream_t stream)
{
  const int*   species  = (const int*)  d_in[0];
  const float* pos      = (const float*)d_in[1];
  const int*   ei       = (const int*)  d_in[2];
  const int*   batch    = (const int*)  d_in[3];
  const float* emb      = (const float*)d_in[4];
  const float* freqs    = (const float*)d_in[5];
  const float* rW1      = (const float*)d_in[6];
  const float* rb1      = (const float*)d_in[7];
  const float* rW2      = (const float*)d_in[8];
  const float* rb2      = (const float*)d_in[9];
  const float* rW3      = (const float*)d_in[10];
  const float* rb3      = (const float*)d_in[11];
  const float* Wss      = (const float*)d_in[12];
  const float* bss      = (const float*)d_in[13];
  const float* Wvv      = (const float*)d_in[14];
  const float* bn_gs    = (const float*)d_in[15];
  const float* bn_bs    = (const float*)d_in[16];
  const float* bn_gv    = (const float*)d_in[17];
  const float* W_out    = (const float*)d_in[18];
  const float* b_out    = (const float*)d_in[19];
  const float* atom_ref = (const float*)d_in[20];

  float* ws = (float*)d_ws;
  size_t off = 0;
  float* basis  = ws + off; off += (size_t)N_EDGES * NB;     // fb path only
  float* Y1     = ws + off; off += (size_t)N_EDGES * 3;
  float* distb  = ws + off; off += (size_t)N_EDGES;
  float* s      = ws + off; off += (size_t)N_NODES * C;
  float* v      = ws + off; off += (size_t)N_NODES * C * 3;
  float* s_new  = ws + off; off += (size_t)N_NODES * C;
  float* v_new  = ws + off; off += (size_t)N_NODES * C * 3;
  double* bn_sums = (double*)(ws + off); off += 192;
  float* scales = ws + off; off += 96;

  // --- region A (sorted + table path) ---
  size_t ra = off;
  float* Y1s      = ws + ra;            ra += (size_t)N_EDGES * 3;
  float* dist_s   = ws + ra;            ra += (size_t)N_EDGES;
  int*   srcs     = (int*)(ws + ra);    ra += N_EDGES;
  int*   counts   = (int*)(ws + ra);    ra += N_NODES;
  int*   row_start= (int*)(ws + ra);    ra += N_NODES;
  int*   cursor   = (int*)(ws + ra);    ra += N_NODES;
  int*   bsum     = (int*)(ws + ra);    ra += 256;
  float* h2tab    = ws + ra;            ra += (size_t)NL * TBL * HID;
  float* wtab     = ws + ra;            ra += (size_t)NL * TBL * 128;
  size_t req_sorted = ra * 4;

  // --- region B (fallback atomic path, aliases region A) ---
  size_t rb = off;
  float* agg_sf = ws + rb; rb += (size_t)N_NODES * C;
  float* agg_sg = ws + rb; rb += (size_t)N_NODES * C;
  float* agg_v  = ws + rb; rb += (size_t)N_NODES * C * 3;

  dim3 b256(256);
  const int gE  = (N_EDGES + 255) / 256;
  const int gNC = (N_NODES * C + 255) / 256;
  const int gN  = (N_NODES + 255) / 256;

  hipMemsetAsync(v, 0, (size_t)N_NODES * C * 3 * sizeof(float), stream);
  k_edge_geom<<<gE, b256, 0, stream>>>(pos, ei, freqs, basis, Y1, distb);
  k_node_init<<<gNC, b256, 0, stream>>>(species, emb, s);

  if (ws_size >= req_sorted) {
    hipMemsetAsync(counts, 0, N_NODES * sizeof(int), stream);
    hipMemsetAsync(cursor, 0, N_NODES * sizeof(int), stream);
    k_hist<<<gE, b256, 0, stream>>>(ei, counts);
    k_scanA<<<NBLK_N, b256, 0, stream>>>(counts, bsum);
    k_scanB<<<1, 64, 0, stream>>>(bsum);
    k_scanC<<<NBLK_N, b256, 0, stream>>>(counts, bsum, row_start);
    k_scatter<<<gE, b256, 0, stream>>>(ei, row_start, cursor, Y1, distb,
                                       srcs, Y1s, dist_s);
    k_table_h<<<(NL*TBL)/256, b256, 0, stream>>>(freqs, rW1, rb1, rW2, rb2, h2tab);
    k_table_w<<<(NL*TBL*16)/256, b256, 0, stream>>>(h2tab, rW3, rb3, wtab);

    for (int l = 0; l < NL; l++) {
      hipMemsetAsync(bn_sums, 0, 96 * sizeof(double), stream);
      k_agg_update<<<(N_NODES*C)/256, b256, 0, stream>>>(
          wtab + (size_t)l * TBL * 128, dist_s, Y1s, srcs,
          row_start, counts, s, v, Wss + l*C*C, bss + l*C, Wvv + l*C*C,
          s_new, v_new);
      k_bn_stats<<<BN_BLOCKS, b256, 0, stream>>>(s_new, v_new, bn_sums);
      k_bn_scales<<<1, 64, 0, stream>>>(bn_sums, bn_gs + l*C, bn_gv + l*C, scales);
      k_apply<<<gNC, b256, 0, stream>>>(s_new, v_new, scales, bn_bs + l*C, s, v);
    }
  } else {
    for (int l = 0; l < NL; l++) {
      hipMemsetAsync(agg_sf, 0, (size_t)N_NODES * 5 * C * sizeof(float), stream);
      hipMemsetAsync(bn_sums, 0, 96 * sizeof(double), stream);
      k_edge_msg_fb<<<gE, b256, 0, stream>>>(basis, Y1, ei, s, v,
          rW1 + l*NB*HID, rb1 + l*HID, rW2 + l*HID*HID, rb2 + l*HID,
          rW3 + l*HID*4*C, rb3 + l*4*C, agg_sf, agg_sg, agg_v);
      k_node_update_fb<<<(N_NODES*C)/256, b256, 0, stream>>>(agg_sf, agg_sg, agg_v,
          Wss + l*C*C, bss + l*C, Wvv + l*C*C, s_new, v_new, bn_sums);
      k_bn_scales<<<1, 64, 0, stream>>>(bn_sums, bn_gs + l*C, bn_gv + l*C, scales);
      k_apply<<<gNC, b256, 0, stream>>>(s_new, v_new, scales, bn_bs + l*C, s, v);
    }
  }

  hipMemsetAsync(d_out, 0, NG * sizeof(float), stream);
  k_readout<<<gN, b256, 0, stream>>>(s, species, batch, W_out, b_out, atom_ref, (float*)d_out);
}

// Round 13
// 332.498 us; speedup vs baseline: 2.2683x; 1.0157x over previous
//
#include <hip/hip_runtime.h>
#include <math.h>

#define N_NODES 50000
#define N_EDGES 400000
#define C 32
#define NB 8
#define HID 64
#define NL 2
#define NG 64
#define RMAXF 5.0f
#define EPSF 1e-5f
#define TBL 4096
#define BN_BLOCKS 512
#define NBLK_N ((N_NODES + 255) / 256)   // 196

__device__ __forceinline__ float silu_f(float x) { return x / (1.0f + __expf(-x)); }
__device__ __forceinline__ float sigmoid_f(float x) { return 1.0f / (1.0f + __expf(-x)); }
__device__ __forceinline__ void atomAddF(float* p, float val) {
  __hip_atomic_fetch_add(p, val, __ATOMIC_RELAXED, __HIP_MEMORY_SCOPE_AGENT);
}
__device__ __forceinline__ void atomAddD(double* p, double val) {
  __hip_atomic_fetch_add(p, val, __ATOMIC_RELAXED, __HIP_MEMORY_SCOPE_AGENT);
}
__device__ __forceinline__ unsigned short bf16_rne(float f) {
  unsigned u = __float_as_uint(f);
  return (unsigned short)((u + 0x7FFFu + ((u >> 16) & 1u)) >> 16);
}
__device__ __forceinline__ float bfu(unsigned short u) {
  return __uint_as_float(((unsigned)u) << 16);
}

// ---------------- fb-only edge geometry (with basis) ----------------
__global__ __launch_bounds__(256) void k_edge_geom(
    const float* __restrict__ pos, const int* __restrict__ ei,
    const float* __restrict__ freqs,
    float* __restrict__ basis, float* __restrict__ Y1)
{
  int e = blockIdx.x * 256 + threadIdx.x;
  if (e >= N_EDGES) return;
  int s = ei[e], d = ei[N_EDGES + e];
  float vx = pos[d*3+0] - pos[s*3+0];
  float vy = pos[d*3+1] - pos[s*3+1];
  float vz = pos[d*3+2] - pos[s*3+2];
  float dist = sqrtf(vx*vx + vy*vy + vz*vz);
  float invd = 1.0f / fmaxf(dist, 1e-9f);
  Y1[e*3+0] = vx*invd; Y1[e*3+1] = vy*invd; Y1[e*3+2] = vz*invd;
  float x = fminf(fmaxf(dist * (1.0f/RMAXF), 0.0f), 1.0f);
  float x2 = x*x, x3 = x2*x;
  float cut = 1.0f - x3 * (10.0f - 15.0f*x + 6.0f*x2);
  if (dist > RMAXF) cut = 0.0f;
  float rinv = cut / fmaxf(dist, 1e-6f);
  #pragma unroll
  for (int k = 0; k < NB; k++)
    basis[e*NB + k] = sinf(freqs[k] * dist) * rinv;
}

// ---------------- node init: s fp32 + s_bf bf16 ----------------
__global__ __launch_bounds__(256) void k_node_init(
    const int* __restrict__ species, const float* __restrict__ emb,
    float* __restrict__ s, unsigned short* __restrict__ s_bf)
{
  int i = blockIdx.x * 256 + threadIdx.x;
  if (i >= N_NODES * C) return;
  int n = i >> 5, c = i & 31;
  float x = emb[species[n]*C + c];
  s[i] = x;
  s_bf[i] = bf16_rne(x);
}

// ---------------- CSR build ----------------
__global__ __launch_bounds__(256) void k_hist(const int* __restrict__ ei, int* __restrict__ counts)
{
  int e = blockIdx.x * 256 + threadIdx.x;
  if (e >= N_EDGES) return;
  atomicAdd(&counts[ei[N_EDGES + e]], 1);
}

__global__ __launch_bounds__(256) void k_scanA(const int* __restrict__ counts, int* __restrict__ bsum)
{
  __shared__ int sh[256];
  int i = blockIdx.x * 256 + threadIdx.x;
  int x = (i < N_NODES) ? counts[i] : 0;
  sh[threadIdx.x] = x;
  __syncthreads();
  for (int off = 128; off > 0; off >>= 1) {
    if (threadIdx.x < off) sh[threadIdx.x] += sh[threadIdx.x + off];
    __syncthreads();
  }
  if (threadIdx.x == 0) bsum[blockIdx.x] = sh[0];
}

// parallel exclusive scan of the 196 block sums (was a 1-thread loop ~25us)
__global__ __launch_bounds__(256) void k_scanB(int* __restrict__ bsum)
{
  __shared__ int sh[256];
  int tid = threadIdx.x;
  int x = (tid < NBLK_N) ? bsum[tid] : 0;
  sh[tid] = x;
  __syncthreads();
  for (int off = 1; off < 256; off <<= 1) {
    int y = (tid >= off) ? sh[tid - off] : 0;
    __syncthreads();
    sh[tid] += y;
    __syncthreads();
  }
  if (tid < NBLK_N) bsum[tid] = sh[tid] - x;   // exclusive
}

__global__ __launch_bounds__(256) void k_scanC(const int* __restrict__ counts,
                                               const int* __restrict__ bsum,
                                               int* __restrict__ row_start)
{
  __shared__ int sh[256];
  int i = blockIdx.x * 256 + threadIdx.x;
  int x = (i < N_NODES) ? counts[i] : 0;
  sh[threadIdx.x] = x;
  __syncthreads();
  for (int off = 1; off < 256; off <<= 1) {
    int y = (threadIdx.x >= off) ? sh[threadIdx.x - off] : 0;
    __syncthreads();
    sh[threadIdx.x] += y;
    __syncthreads();
  }
  if (i < N_NODES) row_start[i] = bsum[blockIdx.x] + sh[threadIdx.x] - x; // exclusive
}

// ---------------- fused geometry + scatter (sorted path; no basis round-trip) -----
__global__ __launch_bounds__(256) void k_geom_scatter(
    const float* __restrict__ pos, const int* __restrict__ ei,
    const int* __restrict__ row_start, int* __restrict__ cursor,
    int* __restrict__ srcs, float* __restrict__ Y1s, float* __restrict__ dist_s)
{
  int e = blockIdx.x * 256 + threadIdx.x;
  if (e >= N_EDGES) return;
  int s = ei[e], d = ei[N_EDGES + e];
  float vx = pos[d*3+0] - pos[s*3+0];
  float vy = pos[d*3+1] - pos[s*3+1];
  float vz = pos[d*3+2] - pos[s*3+2];
  float dist = sqrtf(vx*vx + vy*vy + vz*vz);
  float invd = 1.0f / fmaxf(dist, 1e-9f);
  int p = row_start[d] + atomicAdd(&cursor[d], 1);
  srcs[p] = s;
  dist_s[p] = dist;
  Y1s[p*3+0] = vx*invd;
  Y1s[p*3+1] = vy*invd;
  Y1s[p*3+2] = vz*invd;
}

// ---------------- radial-MLP tabulation ----------------
__global__ __launch_bounds__(256) void k_table_h(
    const float* __restrict__ freqs,
    const float* __restrict__ rW1, const float* __restrict__ rb1,
    const float* __restrict__ rW2, const float* __restrict__ rb2,
    float* __restrict__ h2tab)                 // [NL*TBL*HID]
{
  int idx = blockIdx.x * 256 + threadIdx.x;    // [NL*TBL]
  if (idx >= NL * TBL) return;
  int l = idx / TBL, i = idx - l * TBL;
  float d = (float)i * (RMAXF / (float)(TBL - 1));
  float x = fminf(fmaxf(d * (1.0f/RMAXF), 0.0f), 1.0f);
  float x2 = x*x, x3 = x2*x;
  float cut = 1.0f - x3 * (10.0f - 15.0f*x + 6.0f*x2);
  float rinv = cut / fmaxf(d, 1e-6f);
  float bas[NB];
  #pragma unroll
  for (int k = 0; k < NB; k++) bas[k] = sinf(freqs[k] * d) * rinv;

  const float* W1 = rW1 + l*NB*HID;
  const float* B1 = rb1 + l*HID;
  const float* W2 = rW2 + l*HID*HID;
  const float* B2 = rb2 + l*HID;

  float h2[HID];
  #pragma unroll
  for (int j = 0; j < HID; j++) h2[j] = B2[j];
  #pragma unroll 2
  for (int k = 0; k < HID; k++) {
    float t = B1[k];
    #pragma unroll
    for (int b = 0; b < NB; b++) t = fmaf(bas[b], W1[b*HID + k], t);
    float h1k = silu_f(t);
    const float* r = W2 + k*HID;
    #pragma unroll
    for (int j = 0; j < HID; j++) h2[j] = fmaf(h1k, r[j], h2[j]);
  }
  float* out = h2tab + (size_t)idx * HID;
  #pragma unroll
  for (int j = 0; j < HID; j++) out[j] = silu_f(h2[j]);
}

__global__ __launch_bounds__(256) void k_table_w(
    const float* __restrict__ h2tab,
    const float* __restrict__ rW3, const float* __restrict__ rb3,
    float* __restrict__ wtab)                  // [NL*TBL*128]
{
  int idx = blockIdx.x * 256 + threadIdx.x;    // [NL*TBL*16]
  if (idx >= NL * TBL * 16) return;
  int chunk = idx & 15;
  int row   = idx >> 4;                        // l*TBL + i
  int l     = row / TBL;
  const float* h2 = h2tab + (size_t)row * HID;
  const float* W3 = rW3 + l*HID*4*C + chunk*8;
  const float* B3 = rb3 + l*4*C + chunk*8;
  float a[8];
  #pragma unroll
  for (int ci = 0; ci < 8; ci++) a[ci] = B3[ci];
  #pragma unroll 4
  for (int k = 0; k < HID; k++) {
    float h = h2[k];
    #pragma unroll
    for (int ci = 0; ci < 8; ci++) a[ci] = fmaf(h, W3[k*4*C + ci], a[ci]);
  }
  float* out = wtab + (size_t)row * 128 + chunk*8;
  #pragma unroll
  for (int ci = 0; ci < 8; ci++) out[ci] = a[ci];
}

// ---------------- aggregate (table lerp, bf16 gathers) + gate + self-interaction --
// 32 lanes/node; bf16 node features halve the random-gather traffic
// (512B -> 256B per edge; working set 25.6MB -> 12.8MB, better L2 residency).
__global__ __launch_bounds__(256) void k_agg_update(
    const float* __restrict__ tb,              // this layer's wtab [TBL][128]
    const float* __restrict__ dist_s, const float* __restrict__ Y1s,
    const int* __restrict__ srcs,
    const int* __restrict__ row_start, const int* __restrict__ counts,
    const unsigned short* __restrict__ s_bf, const unsigned short* __restrict__ v_bf,
    const float* __restrict__ Wss, const float* __restrict__ bss,
    const float* __restrict__ Wvv,
    float* __restrict__ s_new, float* __restrict__ v_new)
{
  int t = blockIdx.x * 256 + threadIdx.x;
  int n = t >> 5;
  int c = t & 31;

  const float SCALE = (float)(TBL - 1) / RMAXF;
  float asf = 0.0f, asg = 0.0f, av0 = 0.0f, av1 = 0.0f, av2 = 0.0f;
  int beg = row_start[n], cnt = counts[n];

  int i = 0;
  for (; i + 1 < cnt; i += 2) {
    int pA = beg + i, pB = beg + i + 1;
    float dA = dist_s[pA],  dB = dist_s[pB];
    int srcA = srcs[pA],    srcB = srcs[pB];
    float yA0 = Y1s[pA*3+0], yA1 = Y1s[pA*3+1], yA2 = Y1s[pA*3+2];
    float yB0 = Y1s[pB*3+0], yB1 = Y1s[pB*3+1], yB2 = Y1s[pB*3+2];

    float tsA = fminf(dA, RMAXF) * SCALE;
    int t0A = (int)tsA; t0A = t0A > TBL-2 ? TBL-2 : t0A;
    float frA = tsA - (float)t0A;
    float tsB = fminf(dB, RMAXF) * SCALE;
    int t0B = (int)tsB; t0B = t0B > TBL-2 ? TBL-2 : t0B;
    float frB = tsB - (float)t0B;

    const float* rA0 = tb + (size_t)t0A * 128 + c;
    const float* rA1 = rA0 + 128;
    const float* rB0 = tb + (size_t)t0B * 128 + c;
    const float* rB1 = rB0 + 128;

    float a00 = rA0[0],  a01 = rA1[0];
    float a10 = rA0[32], a11 = rA1[32];
    float a20 = rA0[64], a21 = rA1[64];
    float a30 = rA0[96], a31 = rA1[96];
    float b00 = rB0[0],  b01 = rB1[0];
    float b10 = rB0[32], b11 = rB1[32];
    float b20 = rB0[64], b21 = rB1[64];
    float b30 = rB0[96], b31 = rB1[96];

    float xsA = bfu(s_bf[srcA*C + c]);
    const unsigned short* vpA = v_bf + (size_t)(srcA*C + c)*3;
    float xvA0 = bfu(vpA[0]), xvA1 = bfu(vpA[1]), xvA2 = bfu(vpA[2]);
    float xsB = bfu(s_bf[srcB*C + c]);
    const unsigned short* vpB = v_bf + (size_t)(srcB*C + c)*3;
    float xvB0 = bfu(vpB[0]), xvB1 = bfu(vpB[1]), xvB2 = bfu(vpB[2]);

    float w1A = fmaf(frA, a01-a00, a00);
    float w2A = fmaf(frA, a11-a10, a10);
    float w3A = fmaf(frA, a21-a20, a20);
    float w4A = fmaf(frA, a31-a30, a30);
    asf = fmaf(w1A, xsA, asf);
    asg = fmaf(w2A, xvA0*yA0 + xvA1*yA1 + xvA2*yA2, asg);
    float w3xsA = w3A * xsA;
    av0 += fmaf(w3xsA, yA0, w4A*xvA0);
    av1 += fmaf(w3xsA, yA1, w4A*xvA1);
    av2 += fmaf(w3xsA, yA2, w4A*xvA2);

    float w1B = fmaf(frB, b01-b00, b00);
    float w2B = fmaf(frB, b11-b10, b10);
    float w3B = fmaf(frB, b21-b20, b20);
    float w4B = fmaf(frB, b31-b30, b30);
    asf = fmaf(w1B, xsB, asf);
    asg = fmaf(w2B, xvB0*yB0 + xvB1*yB1 + xvB2*yB2, asg);
    float w3xsB = w3B * xsB;
    av0 += fmaf(w3xsB, yB0, w4B*xvB0);
    av1 += fmaf(w3xsB, yB1, w4B*xvB1);
    av2 += fmaf(w3xsB, yB2, w4B*xvB2);
  }
  if (i < cnt) {
    int p = beg + i;
    float d  = dist_s[p];
    int src = srcs[p];
    float y0 = Y1s[p*3+0], y1 = Y1s[p*3+1], y2 = Y1s[p*3+2];
    float ts = fminf(d, RMAXF) * SCALE;
    int   t0 = (int)ts; t0 = t0 > TBL-2 ? TBL-2 : t0;
    float fr = ts - (float)t0;
    const float* r0 = tb + (size_t)t0 * 128 + c;
    const float* r1 = r0 + 128;
    float w1 = fmaf(fr, r1[0]  - r0[0],  r0[0]);
    float w2 = fmaf(fr, r1[32] - r0[32], r0[32]);
    float w3 = fmaf(fr, r1[64] - r0[64], r0[64]);
    float w4 = fmaf(fr, r1[96] - r0[96], r0[96]);
    float xs = bfu(s_bf[src*C + c]);
    const unsigned short* vp = v_bf + (size_t)(src*C + c)*3;
    float xv0 = bfu(vp[0]), xv1 = bfu(vp[1]), xv2 = bfu(vp[2]);
    asf = fmaf(w1, xs, asf);
    asg = fmaf(w2, xv0*y0 + xv1*y1 + xv2*y2, asg);
    float w3xs = w3 * xs;
    av0 += fmaf(w3xs, y0, w4*xv0);
    av1 += fmaf(w3xs, y1, w4*xv1);
    av2 += fmaf(w3xs, y2, w4*xv2);
  }

  float sgv  = silu_f(asf);
  float gate = sigmoid_f(asg);
  float vg0 = gate*av0, vg1 = gate*av1, vg2 = gate*av2;

  // self-interaction: 32x32 mix via lane broadcast
  float sn = bss[c];
  float vm0 = 0.0f, vm1 = 0.0f, vm2 = 0.0f;
  #pragma unroll
  for (int k = 0; k < C; k++) {
    float a  = __shfl(sgv, k, 32);
    sn = fmaf(a, Wss[k*C + c], sn);
    float wv = Wvv[k*C + c];
    vm0 = fmaf(__shfl(vg0, k, 32), wv, vm0);
    vm1 = fmaf(__shfl(vg1, k, 32), wv, vm1);
    vm2 = fmaf(__shfl(vg2, k, 32), wv, vm2);
  }

  s_new[n*C + c] = sn;
  float* vo = v_new + (size_t)(n*C + c)*3;
  vo[0] = vm0; vo[1] = vm1; vo[2] = vm2;
}

// ---------------- BN stats (grid-stride, register accumulation) ----------------
__global__ __launch_bounds__(256) void k_bn_stats(
    const float* __restrict__ s_new, const float* __restrict__ v_new,
    double* __restrict__ bn_sums)
{
  __shared__ float lacc[3*C];
  if (threadIdx.x < 3*C) lacc[threadIdx.x] = 0.0f;
  __syncthreads();
  int c = threadIdx.x & 31;
  float r1 = 0.0f, r2 = 0.0f, r3 = 0.0f;
  const int NC = N_NODES * C;
  for (int i = blockIdx.x * 256 + threadIdx.x; i < NC; i += BN_BLOCKS * 256) {
    float sn = s_new[i];
    const float* vp = v_new + (size_t)i * 3;
    r1 += sn;
    r2 += sn * sn;
    r3 += vp[0]*vp[0] + vp[1]*vp[1] + vp[2]*vp[2];
  }
  atomicAdd(&lacc[c],       r1);
  atomicAdd(&lacc[C + c],   r2);
  atomicAdd(&lacc[2*C + c], r3);
  __syncthreads();
  if (threadIdx.x < 3*C) atomAddD(&bn_sums[threadIdx.x], (double)lacc[threadIdx.x]);
}

// ---------------- apply BN + residual (scales derived inline) + bf16 mirror -------
__global__ __launch_bounds__(256) void k_apply(
    const float* __restrict__ s_new, const float* __restrict__ v_new,
    const double* __restrict__ bn_sums,
    const float* __restrict__ gs, const float* __restrict__ gv,
    const float* __restrict__ bn_bs,
    float* __restrict__ s, float* __restrict__ v,
    unsigned short* __restrict__ s_bf, unsigned short* __restrict__ v_bf)
{
  int i = blockIdx.x * 256 + threadIdx.x;
  if (i >= N_NODES * C) return;
  int c = i & 31;
  double S1 = bn_sums[c], S2 = bn_sums[C + c], VN = bn_sums[2*C + c];
  float mu  = (float)(S1 / (double)N_NODES);
  float var = (float)(S2 / (double)N_NODES) - mu*mu;
  float vn2 = (float)(VN / (3.0 * (double)N_NODES));
  float ssc = gs[c] / sqrtf(var + EPSF);
  float vsc = gv[c] / sqrtf(vn2 + EPSF);

  float sv = s[i] + (s_new[i] - mu) * ssc + bn_bs[c];
  s[i] = sv;
  s_bf[i] = bf16_rne(sv);
  float* vp = v + (size_t)i*3;
  const float* vn = v_new + (size_t)i*3;
  unsigned short* vb = v_bf + (size_t)i*3;
  #pragma unroll
  for (int d = 0; d < 3; d++) {
    float vv = vp[d] + vn[d] * vsc;
    vp[d] = vv;
    vb[d] = bf16_rne(vv);
  }
}

// ---------------- readout ----------------
__global__ __launch_bounds__(256) void k_readout(
    const float* __restrict__ s, const int* __restrict__ species,
    const int* __restrict__ batch,
    const float* __restrict__ W_out, const float* __restrict__ b_out,
    const float* __restrict__ atom_ref, float* __restrict__ out)
{
  __shared__ float acc[NG];
  if (threadIdx.x < NG) acc[threadIdx.x] = 0.0f;
  __syncthreads();
  int n = blockIdx.x * 256 + threadIdx.x;
  if (n < N_NODES) {
    float e = b_out[0] + atom_ref[species[n]];
    #pragma unroll
    for (int c = 0; c < C; c++) e = fmaf(s[n*C + c], W_out[c], e);
    atomicAdd(&acc[batch[n]], e);
  }
  __syncthreads();
  if (threadIdx.x < NG) {
    float a = acc[threadIdx.x];
    if (a != 0.0f) atomAddF(&out[threadIdx.x], a);
  }
}

// ================= FALLBACK (atomic path, used only if ws too small) ==========
__global__ __launch_bounds__(256) void k_edge_msg_fb(
    const float* __restrict__ basis, const float* __restrict__ Y1,
    const int* __restrict__ ei,
    const float* __restrict__ s, const float* __restrict__ v,
    const float* __restrict__ rW1, const float* __restrict__ rb1,
    const float* __restrict__ rW2, const float* __restrict__ rb2,
    const float* __restrict__ rW3, const float* __restrict__ rb3,
    float* __restrict__ agg_sf, float* __restrict__ agg_sg, float* __restrict__ agg_v)
{
  int e = blockIdx.x * 256 + threadIdx.x;
  if (e >= N_EDGES) return;
  int src = ei[e], dst = ei[N_EDGES + e];
  const float4 b0 = *(const float4*)(basis + (size_t)e*NB);
  const float4 b1 = *(const float4*)(basis + (size_t)e*NB + 4);
  float bas[NB] = {b0.x, b0.y, b0.z, b0.w, b1.x, b1.y, b1.z, b1.w};
  float h2[HID];
  #pragma unroll
  for (int j = 0; j < HID; j++) h2[j] = rb2[j];
  #pragma unroll 2
  for (int k = 0; k < HID; k++) {
    float t = rb1[k];
    #pragma unroll
    for (int b = 0; b < NB; b++) t = fmaf(bas[b], rW1[b*HID + k], t);
    float h1k = silu_f(t);
    const float* r = rW2 + k*HID;
    #pragma unroll
    for (int j = 0; j < HID; j++) h2[j] = fmaf(h1k, r[j], h2[j]);
  }
  #pragma unroll
  for (int j = 0; j < HID; j++) h2[j] = silu_f(h2[j]);
  float y0 = Y1[e*3+0], y1 = Y1[e*3+1], y2 = Y1[e*3+2];
  #pragma unroll 1
  for (int cb = 0; cb < 16; cb++) {
    float a[8];
    #pragma unroll
    for (int ci = 0; ci < 8; ci++) a[ci] = rb3[cb*8 + ci];
    #pragma unroll
    for (int k = 0; k < HID; k++) {
      float h = h2[k];
      #pragma unroll
      for (int ci = 0; ci < 8; ci++) a[ci] = fmaf(h, rW3[k*4*C + cb*8 + ci], a[ci]);
    }
    #pragma unroll
    for (int ci = 0; ci < 8; ci++) {
      int o = cb*8 + ci;
      int path = o >> 5;
      int c = o & 31;
      float xs = s[src*C + c];
      const float* vp = v + (size_t)(src*C + c)*3;
      float xv0 = vp[0], xv1 = vp[1], xv2 = vp[2];
      if (path == 0) {
        atomAddF(&agg_sf[dst*C + c], a[ci] * xs);
      } else if (path == 1) {
        atomAddF(&agg_sg[dst*C + c], a[ci] * (xv0*y0 + xv1*y1 + xv2*y2));
      } else if (path == 2) {
        float w3xs = a[ci] * xs;
        float* ap = agg_v + (size_t)(dst*C + c)*3;
        atomAddF(ap+0, w3xs*y0); atomAddF(ap+1, w3xs*y1); atomAddF(ap+2, w3xs*y2);
      } else {
        float* ap = agg_v + (size_t)(dst*C + c)*3;
        atomAddF(ap+0, a[ci]*xv0); atomAddF(ap+1, a[ci]*xv1); atomAddF(ap+2, a[ci]*xv2);
      }
    }
  }
}

__global__ __launch_bounds__(256) void k_node_update_fb(
    const float* __restrict__ agg_sf, const float* __restrict__ agg_sg,
    const float* __restrict__ agg_v,
    const float* __restrict__ Wss, const float* __restrict__ bss,
    const float* __restrict__ Wvv,
    float* __restrict__ s_new, float* __restrict__ v_new,
    double* __restrict__ bn_sums)
{
  __shared__ float lacc[3*C];
  int t = blockIdx.x * 256 + threadIdx.x;
  int n = t >> 5;
  int c = t & 31;
  if (threadIdx.x < 3*C) lacc[threadIdx.x] = 0.0f;
  __syncthreads();
  float asf = agg_sf[n*C + c];
  float asg = agg_sg[n*C + c];
  const float* ap = agg_v + (size_t)(n*C + c)*3;
  float av0 = ap[0], av1 = ap[1], av2 = ap[2];
  float sgv = silu_f(asf);
  float gate = sigmoid_f(asg);
  float vg0 = gate*av0, vg1 = gate*av1, vg2 = gate*av2;
  float sn = bss[c];
  float vm0 = 0.0f, vm1 = 0.0f, vm2 = 0.0f;
  #pragma unroll
  for (int k = 0; k < C; k++) {
    float a  = __shfl(sgv, k, 32);
    sn = fmaf(a, Wss[k*C + c], sn);
    float wv = Wvv[k*C + c];
    vm0 = fmaf(__shfl(vg0, k, 32), wv, vm0);
    vm1 = fmaf(__shfl(vg1, k, 32), wv, vm1);
    vm2 = fmaf(__shfl(vg2, k, 32), wv, vm2);
  }
  s_new[n*C + c] = sn;
  float* vo = v_new + (size_t)(n*C + c)*3;
  vo[0] = vm0; vo[1] = vm1; vo[2] = vm2;
  float vn2 = vm0*vm0 + vm1*vm1 + vm2*vm2;
  atomicAdd(&lacc[c], sn);
  atomicAdd(&lacc[C + c], sn*sn);
  atomicAdd(&lacc[2*C + c], vn2);
  __syncthreads();
  if (threadIdx.x < 3*C) atomAddD(&bn_sums[threadIdx.x], (double)lacc[threadIdx.x]);
}

__global__ void k_bn_scales_fb(const double* __restrict__ bn_sums,
                               const float* __restrict__ gs, const float* __restrict__ gv,
                               float* __restrict__ scales)
{
  int m = threadIdx.x;
  if (m >= C) return;
  double S1 = bn_sums[m], S2 = bn_sums[C + m], VN = bn_sums[2*C + m];
  double mu  = S1 / (double)N_NODES;
  double var = S2 / (double)N_NODES - mu*mu;
  double vn2 = VN / (3.0 * (double)N_NODES);
  scales[m]       = (float)mu;
  scales[C + m]   = gs[m] / sqrtf((float)var + EPSF);
  scales[2*C + m] = gv[m] / sqrtf((float)vn2 + EPSF);
}

__global__ __launch_bounds__(256) void k_apply_fb(
    const float* __restrict__ s_new, const float* __restrict__ v_new,
    const float* __restrict__ scales, const float* __restrict__ bn_bs,
    float* __restrict__ s, float* __restrict__ v)
{
  int i = blockIdx.x * 256 + threadIdx.x;
  if (i >= N_NODES * C) return;
  int c = i & 31;
  s[i] += (s_new[i] - scales[c]) * scales[C + c] + bn_bs[c];
  float vs = scales[2*C + c];
  v[(size_t)i*3+0] += v_new[(size_t)i*3+0] * vs;
  v[(size_t)i*3+1] += v_new[(size_t)i*3+1] * vs;
  v[(size_t)i*3+2] += v_new[(size_t)i*3+2] * vs;
}

extern "C" void kernel_launch(void* const* d_in, const int* in_sizes, int n_in,
                              void* d_out, int out_size, void* d_ws, size_t ws_size,
                              hipStream_t stream)
{
  const int*   species  = (const int*)  d_in[0];
  const float* pos      = (const float*)d_in[1];
  const int*   ei       = (const int*)  d_in[2];
  const int*   batch    = (const int*)  d_in[3];
  const float* emb      = (const float*)d_in[4];
  const float* freqs    = (const float*)d_in[5];
  const float* rW1      = (const float*)d_in[6];
  const float* rb1      = (const float*)d_in[7];
  const float* rW2      = (const float*)d_in[8];
  const float* rb2      = (const float*)d_in[9];
  const float* rW3      = (const float*)d_in[10];
  const float* rb3      = (const float*)d_in[11];
  const float* Wss      = (const float*)d_in[12];
  const float* bss      = (const float*)d_in[13];
  const float* Wvv      = (const float*)d_in[14];
  const float* bn_gs    = (const float*)d_in[15];
  const float* bn_bs    = (const float*)d_in[16];
  const float* bn_gv    = (const float*)d_in[17];
  const float* W_out    = (const float*)d_in[18];
  const float* b_out    = (const float*)d_in[19];
  const float* atom_ref = (const float*)d_in[20];

  float* ws = (float*)d_ws;
  size_t off = 0;
  float* basis  = ws + off; off += (size_t)N_EDGES * NB;     // fb path only
  float* Y1     = ws + off; off += (size_t)N_EDGES * 3;      // fb path only
  float* s      = ws + off; off += (size_t)N_NODES * C;
  float* v      = ws + off; off += (size_t)N_NODES * C * 3;
  float* s_new  = ws + off; off += (size_t)N_NODES * C;
  float* v_new  = ws + off; off += (size_t)N_NODES * C * 3;
  double* bn_sums = (double*)(ws + off); off += 192;
  float* scales = ws + off; off += 96;

  // --- region A (sorted + table path) ---
  size_t ra = off;
  float* Y1s      = ws + ra;            ra += (size_t)N_EDGES * 3;
  float* dist_s   = ws + ra;            ra += (size_t)N_EDGES;
  int*   srcs     = (int*)(ws + ra);    ra += N_EDGES;
  int*   counts   = (int*)(ws + ra);    ra += N_NODES;
  int*   row_start= (int*)(ws + ra);    ra += N_NODES;
  int*   cursor   = (int*)(ws + ra);    ra += N_NODES;
  int*   bsum     = (int*)(ws + ra);    ra += 256;
  float* h2tab    = ws + ra;            ra += (size_t)NL * TBL * HID;
  float* wtab     = ws + ra;            ra += (size_t)NL * TBL * 128;
  unsigned short* s_bf = (unsigned short*)(ws + ra); ra += (size_t)N_NODES * C / 2;
  unsigned short* v_bf = (unsigned short*)(ws + ra); ra += (size_t)N_NODES * C * 3 / 2;
  size_t req_sorted = ra * 4;

  // --- region B (fallback atomic path, aliases region A) ---
  size_t rb = off;
  float* agg_sf = ws + rb; rb += (size_t)N_NODES * C;
  float* agg_sg = ws + rb; rb += (size_t)N_NODES * C;
  float* agg_v  = ws + rb; rb += (size_t)N_NODES * C * 3;

  dim3 b256(256);
  const int gE  = (N_EDGES + 255) / 256;
  const int gNC = (N_NODES * C + 255) / 256;
  const int gN  = (N_NODES + 255) / 256;

  hipMemsetAsync(v, 0, (size_t)N_NODES * C * 3 * sizeof(float), stream);

  if (ws_size >= req_sorted) {
    hipMemsetAsync(v_bf, 0, (size_t)N_NODES * C * 3 * sizeof(unsigned short), stream);
    hipMemsetAsync(counts, 0, N_NODES * sizeof(int), stream);
    hipMemsetAsync(cursor, 0, N_NODES * sizeof(int), stream);
    k_node_init<<<gNC, b256, 0, stream>>>(species, emb, s, s_bf);
    k_hist<<<gE, b256, 0, stream>>>(ei, counts);
    k_scanA<<<NBLK_N, b256, 0, stream>>>(counts, bsum);
    k_scanB<<<1, b256, 0, stream>>>(bsum);
    k_scanC<<<NBLK_N, b256, 0, stream>>>(counts, bsum, row_start);
    k_geom_scatter<<<gE, b256, 0, stream>>>(pos, ei, row_start, cursor,
                                            srcs, Y1s, dist_s);
    k_table_h<<<(NL*TBL)/256, b256, 0, stream>>>(freqs, rW1, rb1, rW2, rb2, h2tab);
    k_table_w<<<(NL*TBL*16)/256, b256, 0, stream>>>(h2tab, rW3, rb3, wtab);

    for (int l = 0; l < NL; l++) {
      hipMemsetAsync(bn_sums, 0, 96 * sizeof(double), stream);
      k_agg_update<<<(N_NODES*C)/256, b256, 0, stream>>>(
          wtab + (size_t)l * TBL * 128, dist_s, Y1s, srcs,
          row_start, counts, s_bf, v_bf, Wss + l*C*C, bss + l*C, Wvv + l*C*C,
          s_new, v_new);
      k_bn_stats<<<BN_BLOCKS, b256, 0, stream>>>(s_new, v_new, bn_sums);
      k_apply<<<gNC, b256, 0, stream>>>(s_new, v_new, bn_sums,
          bn_gs + l*C, bn_gv + l*C, bn_bs + l*C, s, v, s_bf, v_bf);
    }
  } else {
    k_node_init<<<gNC, b256, 0, stream>>>(species, emb, s, (unsigned short*)(ws + off)); // scratch bf (unused)
    k_edge_geom<<<gE, b256, 0, stream>>>(pos, ei, freqs, basis, Y1);
    for (int l = 0; l < NL; l++) {
      hipMemsetAsync(agg_sf, 0, (size_t)N_NODES * 5 * C * sizeof(float), stream);
      hipMemsetAsync(bn_sums, 0, 96 * sizeof(double), stream);
      k_edge_msg_fb<<<gE, b256, 0, stream>>>(basis, Y1, ei, s, v,
          rW1 + l*NB*HID, rb1 + l*HID, rW2 + l*HID*HID, rb2 + l*HID,
          rW3 + l*HID*4*C, rb3 + l*4*C, agg_sf, agg_sg, agg_v);
      k_node_update_fb<<<(N_NODES*C)/256, b256, 0, stream>>>(agg_sf, agg_sg, agg_v,
          Wss + l*C*C, bss + l*C, Wvv + l*C*C, s_new, v_new, bn_sums);
      k_bn_scales_fb<<<1, 64, 0, stream>>>(bn_sums, bn_gs + l*C, bn_gv + l*C, scales);
      k_apply_fb<<<gNC, b256, 0, stream>>>(s_new, v_new, scales, bn_bs + l*C, s, v);
    }
  }

  hipMemsetAsync(d_out, 0, NG * sizeof(float), stream);
  k_readout<<<gN, b256, 0, stream>>>(s, species, batch, W_out, b_out, atom_ref, (float*)d_out);
}

// Round 14
// 321.197 us; speedup vs baseline: 2.3481x; 1.0352x over previous
//
#include <hip/hip_runtime.h>
#include <math.h>

#define N_NODES 50000
#define N_EDGES 400000
#define C 32
#define NB 8
#define HID 64
#define NL 2
#define NG 64
#define RMAXF 5.0f
#define EPSF 1e-5f
#define TBL 4096
#define BN_BLOCKS 512
#define NBLK_N ((N_NODES + 255) / 256)   // 196

__device__ __forceinline__ float silu_f(float x) { return x / (1.0f + __expf(-x)); }
__device__ __forceinline__ float sigmoid_f(float x) { return 1.0f / (1.0f + __expf(-x)); }
__device__ __forceinline__ void atomAddF(float* p, float val) {
  __hip_atomic_fetch_add(p, val, __ATOMIC_RELAXED, __HIP_MEMORY_SCOPE_AGENT);
}
__device__ __forceinline__ void atomAddD(double* p, double val) {
  __hip_atomic_fetch_add(p, val, __ATOMIC_RELAXED, __HIP_MEMORY_SCOPE_AGENT);
}
__device__ __forceinline__ unsigned short bf16_rne(float f) {
  unsigned u = __float_as_uint(f);
  return (unsigned short)((u + 0x7FFFu + ((u >> 16) & 1u)) >> 16);
}
__device__ __forceinline__ float bfu(unsigned short u) {
  return __uint_as_float(((unsigned)u) << 16);
}

// ---------------- fb-only edge geometry (with basis) ----------------
__global__ __launch_bounds__(256) void k_edge_geom(
    const float* __restrict__ pos, const int* __restrict__ ei,
    const float* __restrict__ freqs,
    float* __restrict__ basis, float* __restrict__ Y1)
{
  int e = blockIdx.x * 256 + threadIdx.x;
  if (e >= N_EDGES) return;
  int s = ei[e], d = ei[N_EDGES + e];
  float vx = pos[d*3+0] - pos[s*3+0];
  float vy = pos[d*3+1] - pos[s*3+1];
  float vz = pos[d*3+2] - pos[s*3+2];
  float dist = sqrtf(vx*vx + vy*vy + vz*vz);
  float invd = 1.0f / fmaxf(dist, 1e-9f);
  Y1[e*3+0] = vx*invd; Y1[e*3+1] = vy*invd; Y1[e*3+2] = vz*invd;
  float x = fminf(fmaxf(dist * (1.0f/RMAXF), 0.0f), 1.0f);
  float x2 = x*x, x3 = x2*x;
  float cut = 1.0f - x3 * (10.0f - 15.0f*x + 6.0f*x2);
  if (dist > RMAXF) cut = 0.0f;
  float rinv = cut / fmaxf(dist, 1e-6f);
  #pragma unroll
  for (int k = 0; k < NB; k++)
    basis[e*NB + k] = sinf(freqs[k] * dist) * rinv;
}

// ---------------- node init: s fp32 + s_bf bf16 ----------------
__global__ __launch_bounds__(256) void k_node_init(
    const int* __restrict__ species, const float* __restrict__ emb,
    float* __restrict__ s, unsigned short* __restrict__ s_bf)
{
  int i = blockIdx.x * 256 + threadIdx.x;
  if (i >= N_NODES * C) return;
  int n = i >> 5, c = i & 31;
  float x = emb[species[n]*C + c];
  s[i] = x;
  s_bf[i] = bf16_rne(x);
}

// ---------------- CSR build ----------------
__global__ __launch_bounds__(256) void k_hist(const int* __restrict__ ei, int* __restrict__ counts)
{
  int e = blockIdx.x * 256 + threadIdx.x;
  if (e >= N_EDGES) return;
  atomicAdd(&counts[ei[N_EDGES + e]], 1);
}

__global__ __launch_bounds__(256) void k_scanA(const int* __restrict__ counts, int* __restrict__ bsum)
{
  __shared__ int sh[256];
  int i = blockIdx.x * 256 + threadIdx.x;
  int x = (i < N_NODES) ? counts[i] : 0;
  sh[threadIdx.x] = x;
  __syncthreads();
  for (int off = 128; off > 0; off >>= 1) {
    if (threadIdx.x < off) sh[threadIdx.x] += sh[threadIdx.x + off];
    __syncthreads();
  }
  if (threadIdx.x == 0) bsum[blockIdx.x] = sh[0];
}

__global__ __launch_bounds__(256) void k_scanB(int* __restrict__ bsum)
{
  __shared__ int sh[256];
  int tid = threadIdx.x;
  int x = (tid < NBLK_N) ? bsum[tid] : 0;
  sh[tid] = x;
  __syncthreads();
  for (int off = 1; off < 256; off <<= 1) {
    int y = (tid >= off) ? sh[tid - off] : 0;
    __syncthreads();
    sh[tid] += y;
    __syncthreads();
  }
  if (tid < NBLK_N) bsum[tid] = sh[tid] - x;   // exclusive
}

__global__ __launch_bounds__(256) void k_scanC(const int* __restrict__ counts,
                                               const int* __restrict__ bsum,
                                               int* __restrict__ row_start)
{
  __shared__ int sh[256];
  int i = blockIdx.x * 256 + threadIdx.x;
  int x = (i < N_NODES) ? counts[i] : 0;
  sh[threadIdx.x] = x;
  __syncthreads();
  for (int off = 1; off < 256; off <<= 1) {
    int y = (threadIdx.x >= off) ? sh[threadIdx.x - off] : 0;
    __syncthreads();
    sh[threadIdx.x] += y;
    __syncthreads();
  }
  if (i < N_NODES) row_start[i] = bsum[blockIdx.x] + sh[threadIdx.x] - x; // exclusive
}

// ---------------- fused geometry + scatter into packed 32B records ----------------
// rec[p*8] = {dist, src(bits), y0, y1, y2, 0,0,0}: 1 dirtied line per edge (was 3),
// and the agg loop reads it as float4+float (2 loads, was 5).
__global__ __launch_bounds__(256) void k_geom_scatter(
    const float* __restrict__ pos, const int* __restrict__ ei,
    const int* __restrict__ row_start, int* __restrict__ cursor,
    float* __restrict__ rec)
{
  int e = blockIdx.x * 256 + threadIdx.x;
  if (e >= N_EDGES) return;
  int s = ei[e], d = ei[N_EDGES + e];
  float vx = pos[d*3+0] - pos[s*3+0];
  float vy = pos[d*3+1] - pos[s*3+1];
  float vz = pos[d*3+2] - pos[s*3+2];
  float dist = sqrtf(vx*vx + vy*vy + vz*vz);
  float invd = 1.0f / fmaxf(dist, 1e-9f);
  int p = row_start[d] + atomicAdd(&cursor[d], 1);
  float* rp = rec + (size_t)p * 8;
  float4 r0; r0.x = dist; r0.y = __int_as_float(s); r0.z = vx*invd; r0.w = vy*invd;
  *(float4*)rp = r0;
  rp[4] = vz*invd;
}

// ---------------- radial-MLP tabulation ----------------
__global__ __launch_bounds__(256) void k_table_h(
    const float* __restrict__ freqs,
    const float* __restrict__ rW1, const float* __restrict__ rb1,
    const float* __restrict__ rW2, const float* __restrict__ rb2,
    float* __restrict__ h2tab)                 // [NL*TBL*HID]
{
  int idx = blockIdx.x * 256 + threadIdx.x;    // [NL*TBL]
  if (idx >= NL * TBL) return;
  int l = idx / TBL, i = idx - l * TBL;
  float d = (float)i * (RMAXF / (float)(TBL - 1));
  float x = fminf(fmaxf(d * (1.0f/RMAXF), 0.0f), 1.0f);
  float x2 = x*x, x3 = x2*x;
  float cut = 1.0f - x3 * (10.0f - 15.0f*x + 6.0f*x2);
  float rinv = cut / fmaxf(d, 1e-6f);
  float bas[NB];
  #pragma unroll
  for (int k = 0; k < NB; k++) bas[k] = sinf(freqs[k] * d) * rinv;

  const float* W1 = rW1 + l*NB*HID;
  const float* B1 = rb1 + l*HID;
  const float* W2 = rW2 + l*HID*HID;
  const float* B2 = rb2 + l*HID;

  float h2[HID];
  #pragma unroll
  for (int j = 0; j < HID; j++) h2[j] = B2[j];
  #pragma unroll 2
  for (int k = 0; k < HID; k++) {
    float t = B1[k];
    #pragma unroll
    for (int b = 0; b < NB; b++) t = fmaf(bas[b], W1[b*HID + k], t);
    float h1k = silu_f(t);
    const float* r = W2 + k*HID;
    #pragma unroll
    for (int j = 0; j < HID; j++) h2[j] = fmaf(h1k, r[j], h2[j]);
  }
  float* out = h2tab + (size_t)idx * HID;
  #pragma unroll
  for (int j = 0; j < HID; j++) out[j] = silu_f(h2[j]);
}

__global__ __launch_bounds__(256) void k_table_w(
    const float* __restrict__ h2tab,
    const float* __restrict__ rW3, const float* __restrict__ rb3,
    float* __restrict__ wtab)                  // [NL*TBL*128]
{
  int idx = blockIdx.x * 256 + threadIdx.x;    // [NL*TBL*16]
  if (idx >= NL * TBL * 16) return;
  int chunk = idx & 15;
  int row   = idx >> 4;                        // l*TBL + i
  int l     = row / TBL;
  const float* h2 = h2tab + (size_t)row * HID;
  const float* W3 = rW3 + l*HID*4*C + chunk*8;
  const float* B3 = rb3 + l*4*C + chunk*8;
  float a[8];
  #pragma unroll
  for (int ci = 0; ci < 8; ci++) a[ci] = B3[ci];
  #pragma unroll 4
  for (int k = 0; k < HID; k++) {
    float h = h2[k];
    #pragma unroll
    for (int ci = 0; ci < 8; ci++) a[ci] = fmaf(h, W3[k*4*C + ci], a[ci]);
  }
  float* out = wtab + (size_t)row * 128 + chunk*8;
  #pragma unroll
  for (int ci = 0; ci < 8; ci++) out[ci] = a[ci];
}

// ---------------- aggregate: packed records + software-pipelined prefetch ---------
// 32 lanes/node. Records for iteration i+2/i+3 are prefetched while iteration i's
// feature gathers are in flight -> one dependent L2 round trip per iteration
// (r13 had two: index loads THEN gather). Tail handled by validB mask (no branch).
__global__ __launch_bounds__(256) void k_agg_update(
    const float* __restrict__ tb,              // this layer's wtab [TBL][128]
    const float* __restrict__ rec,
    const int* __restrict__ row_start, const int* __restrict__ counts,
    const unsigned short* __restrict__ s_bf, const unsigned short* __restrict__ v_bf,
    const float* __restrict__ Wss, const float* __restrict__ bss,
    const float* __restrict__ Wvv,
    float* __restrict__ s_new, float* __restrict__ v_new)
{
  int t = blockIdx.x * 256 + threadIdx.x;
  int n = t >> 5;
  int c = t & 31;

  const float SCALE = (float)(TBL - 1) / RMAXF;
  float asf = 0.0f, asg = 0.0f, av0 = 0.0f, av1 = 0.0f, av2 = 0.0f;
  int beg = row_start[n], cnt = counts[n];

  if (cnt > 0) {
    int last = beg + cnt - 1;
    int pA = beg, pB = (beg + 1 < last) ? beg + 1 : last;
    float4 rA = *(const float4*)(rec + (size_t)pA * 8);
    float  zA = rec[(size_t)pA * 8 + 4];
    float4 rB = *(const float4*)(rec + (size_t)pB * 8);
    float  zB = rec[(size_t)pB * 8 + 4];

    for (int i = 0; i < cnt; i += 2) {
      // prefetch records for next pair (clamped; harmless if unused)
      int pA2 = beg + i + 2; pA2 = pA2 < last ? pA2 : last;
      int pB2 = beg + i + 3; pB2 = pB2 < last ? pB2 : last;
      float4 rA_n = *(const float4*)(rec + (size_t)pA2 * 8);
      float  zA_n = rec[(size_t)pA2 * 8 + 4];
      float4 rB_n = *(const float4*)(rec + (size_t)pB2 * 8);
      float  zB_n = rec[(size_t)pB2 * 8 + 4];

      float validB = (i + 1 < cnt) ? 1.0f : 0.0f;
      float dA = rA.x;  int srcA = __float_as_int(rA.y);
      float yA0 = rA.z, yA1 = rA.w, yA2 = zA;
      float dB = rB.x;  int srcB = __float_as_int(rB.y);
      float yB0 = rB.z, yB1 = rB.w, yB2 = zB;

      // feature gathers (independent A/B chains)
      float xsA = bfu(s_bf[srcA*C + c]);
      const unsigned short* vpA = v_bf + (size_t)(srcA*C + c)*3;
      float xvA0 = bfu(vpA[0]), xvA1 = bfu(vpA[1]), xvA2 = bfu(vpA[2]);
      float xsB = bfu(s_bf[srcB*C + c]);
      const unsigned short* vpB = v_bf + (size_t)(srcB*C + c)*3;
      float xvB0 = bfu(vpB[0]), xvB1 = bfu(vpB[1]), xvB2 = bfu(vpB[2]);

      // table lerp
      float tsA = fminf(dA, RMAXF) * SCALE;
      int t0A = (int)tsA; t0A = t0A > TBL-2 ? TBL-2 : t0A;
      float frA = tsA - (float)t0A;
      float tsB = fminf(dB, RMAXF) * SCALE;
      int t0B = (int)tsB; t0B = t0B > TBL-2 ? TBL-2 : t0B;
      float frB = tsB - (float)t0B;

      const float* rtA0 = tb + (size_t)t0A * 128 + c;
      const float* rtA1 = rtA0 + 128;
      const float* rtB0 = tb + (size_t)t0B * 128 + c;
      const float* rtB1 = rtB0 + 128;

      float w1A = fmaf(frA, rtA1[0]  - rtA0[0],  rtA0[0]);
      float w2A = fmaf(frA, rtA1[32] - rtA0[32], rtA0[32]);
      float w3A = fmaf(frA, rtA1[64] - rtA0[64], rtA0[64]);
      float w4A = fmaf(frA, rtA1[96] - rtA0[96], rtA0[96]);
      float w1B = validB * fmaf(frB, rtB1[0]  - rtB0[0],  rtB0[0]);
      float w2B = validB * fmaf(frB, rtB1[32] - rtB0[32], rtB0[32]);
      float w3B = validB * fmaf(frB, rtB1[64] - rtB0[64], rtB0[64]);
      float w4B = validB * fmaf(frB, rtB1[96] - rtB0[96], rtB0[96]);

      asf = fmaf(w1A, xsA, asf);
      asg = fmaf(w2A, xvA0*yA0 + xvA1*yA1 + xvA2*yA2, asg);
      float w3xsA = w3A * xsA;
      av0 += fmaf(w3xsA, yA0, w4A*xvA0);
      av1 += fmaf(w3xsA, yA1, w4A*xvA1);
      av2 += fmaf(w3xsA, yA2, w4A*xvA2);

      asf = fmaf(w1B, xsB, asf);
      asg = fmaf(w2B, xvB0*yB0 + xvB1*yB1 + xvB2*yB2, asg);
      float w3xsB = w3B * xsB;
      av0 += fmaf(w3xsB, yB0, w4B*xvB0);
      av1 += fmaf(w3xsB, yB1, w4B*xvB1);
      av2 += fmaf(w3xsB, yB2, w4B*xvB2);

      rA = rA_n; zA = zA_n; rB = rB_n; zB = zB_n;
    }
  }

  float sgv  = silu_f(asf);
  float gate = sigmoid_f(asg);
  float vg0 = gate*av0, vg1 = gate*av1, vg2 = gate*av2;

  // self-interaction: 32x32 mix via lane broadcast
  float sn = bss[c];
  float vm0 = 0.0f, vm1 = 0.0f, vm2 = 0.0f;
  #pragma unroll
  for (int k = 0; k < C; k++) {
    float a  = __shfl(sgv, k, 32);
    sn = fmaf(a, Wss[k*C + c], sn);
    float wv = Wvv[k*C + c];
    vm0 = fmaf(__shfl(vg0, k, 32), wv, vm0);
    vm1 = fmaf(__shfl(vg1, k, 32), wv, vm1);
    vm2 = fmaf(__shfl(vg2, k, 32), wv, vm2);
  }

  s_new[n*C + c] = sn;
  float* vo = v_new + (size_t)(n*C + c)*3;
  vo[0] = vm0; vo[1] = vm1; vo[2] = vm2;
}

// ---------------- BN stats (grid-stride, register accumulation) ----------------
__global__ __launch_bounds__(256) void k_bn_stats(
    const float* __restrict__ s_new, const float* __restrict__ v_new,
    double* __restrict__ bn_sums)
{
  __shared__ float lacc[3*C];
  if (threadIdx.x < 3*C) lacc[threadIdx.x] = 0.0f;
  __syncthreads();
  int c = threadIdx.x & 31;
  float r1 = 0.0f, r2 = 0.0f, r3 = 0.0f;
  const int NC = N_NODES * C;
  for (int i = blockIdx.x * 256 + threadIdx.x; i < NC; i += BN_BLOCKS * 256) {
    float sn = s_new[i];
    const float* vp = v_new + (size_t)i * 3;
    r1 += sn;
    r2 += sn * sn;
    r3 += vp[0]*vp[0] + vp[1]*vp[1] + vp[2]*vp[2];
  }
  atomicAdd(&lacc[c],       r1);
  atomicAdd(&lacc[C + c],   r2);
  atomicAdd(&lacc[2*C + c], r3);
  __syncthreads();
  if (threadIdx.x < 3*C) atomAddD(&bn_sums[threadIdx.x], (double)lacc[threadIdx.x]);
}

// ---------------- apply BN + residual (scales derived inline) + bf16 mirror -------
__global__ __launch_bounds__(256) void k_apply(
    const float* __restrict__ s_new, const float* __restrict__ v_new,
    const double* __restrict__ bn_sums,
    const float* __restrict__ gs, const float* __restrict__ gv,
    const float* __restrict__ bn_bs,
    float* __restrict__ s, float* __restrict__ v,
    unsigned short* __restrict__ s_bf, unsigned short* __restrict__ v_bf)
{
  int i = blockIdx.x * 256 + threadIdx.x;
  if (i >= N_NODES * C) return;
  int c = i & 31;
  double S1 = bn_sums[c], S2 = bn_sums[C + c], VN = bn_sums[2*C + c];
  float mu  = (float)(S1 / (double)N_NODES);
  float var = (float)(S2 / (double)N_NODES) - mu*mu;
  float vn2 = (float)(VN / (3.0 * (double)N_NODES));
  float ssc = gs[c] / sqrtf(var + EPSF);
  float vsc = gv[c] / sqrtf(vn2 + EPSF);

  float sv = s[i] + (s_new[i] - mu) * ssc + bn_bs[c];
  s[i] = sv;
  s_bf[i] = bf16_rne(sv);
  float* vp = v + (size_t)i*3;
  const float* vn = v_new + (size_t)i*3;
  unsigned short* vb = v_bf + (size_t)i*3;
  #pragma unroll
  for (int d = 0; d < 3; d++) {
    float vv = vp[d] + vn[d] * vsc;
    vp[d] = vv;
    vb[d] = bf16_rne(vv);
  }
}

// ---------------- readout ----------------
__global__ __launch_bounds__(256) void k_readout(
    const float* __restrict__ s, const int* __restrict__ species,
    const int* __restrict__ batch,
    const float* __restrict__ W_out, const float* __restrict__ b_out,
    const float* __restrict__ atom_ref, float* __restrict__ out)
{
  __shared__ float acc[NG];
  if (threadIdx.x < NG) acc[threadIdx.x] = 0.0f;
  __syncthreads();
  int n = blockIdx.x * 256 + threadIdx.x;
  if (n < N_NODES) {
    float e = b_out[0] + atom_ref[species[n]];
    #pragma unroll
    for (int c = 0; c < C; c++) e = fmaf(s[n*C + c], W_out[c], e);
    atomicAdd(&acc[batch[n]], e);
  }
  __syncthreads();
  if (threadIdx.x < NG) {
    float a = acc[threadIdx.x];
    if (a != 0.0f) atomAddF(&out[threadIdx.x], a);
  }
}

// ================= FALLBACK (atomic path, used only if ws too small) ==========
__global__ __launch_bounds__(256) void k_edge_msg_fb(
    const float* __restrict__ basis, const float* __restrict__ Y1,
    const int* __restrict__ ei,
    const float* __restrict__ s, const float* __restrict__ v,
    const float* __restrict__ rW1, const float* __restrict__ rb1,
    const float* __restrict__ rW2, const float* __restrict__ rb2,
    const float* __restrict__ rW3, const float* __restrict__ rb3,
    float* __restrict__ agg_sf, float* __restrict__ agg_sg, float* __restrict__ agg_v)
{
  int e = blockIdx.x * 256 + threadIdx.x;
  if (e >= N_EDGES) return;
  int src = ei[e], dst = ei[N_EDGES + e];
  const float4 b0 = *(const float4*)(basis + (size_t)e*NB);
  const float4 b1 = *(const float4*)(basis + (size_t)e*NB + 4);
  float bas[NB] = {b0.x, b0.y, b0.z, b0.w, b1.x, b1.y, b1.z, b1.w};
  float h2[HID];
  #pragma unroll
  for (int j = 0; j < HID; j++) h2[j] = rb2[j];
  #pragma unroll 2
  for (int k = 0; k < HID; k++) {
    float t = rb1[k];
    #pragma unroll
    for (int b = 0; b < NB; b++) t = fmaf(bas[b], rW1[b*HID + k], t);
    float h1k = silu_f(t);
    const float* r = rW2 + k*HID;
    #pragma unroll
    for (int j = 0; j < HID; j++) h2[j] = fmaf(h1k, r[j], h2[j]);
  }
  #pragma unroll
  for (int j = 0; j < HID; j++) h2[j] = silu_f(h2[j]);
  float y0 = Y1[e*3+0], y1 = Y1[e*3+1], y2 = Y1[e*3+2];
  #pragma unroll 1
  for (int cb = 0; cb < 16; cb++) {
    float a[8];
    #pragma unroll
    for (int ci = 0; ci < 8; ci++) a[ci] = rb3[cb*8 + ci];
    #pragma unroll
    for (int k = 0; k < HID; k++) {
      float h = h2[k];
      #pragma unroll
      for (int ci = 0; ci < 8; ci++) a[ci] = fmaf(h, rW3[k*4*C + cb*8 + ci], a[ci]);
    }
    #pragma unroll
    for (int ci = 0; ci < 8; ci++) {
      int o = cb*8 + ci;
      int path = o >> 5;
      int c = o & 31;
      float xs = s[src*C + c];
      const float* vp = v + (size_t)(src*C + c)*3;
      float xv0 = vp[0], xv1 = vp[1], xv2 = vp[2];
      if (path == 0) {
        atomAddF(&agg_sf[dst*C + c], a[ci] * xs);
      } else if (path == 1) {
        atomAddF(&agg_sg[dst*C + c], a[ci] * (xv0*y0 + xv1*y1 + xv2*y2));
      } else if (path == 2) {
        float w3xs = a[ci] * xs;
        float* ap = agg_v + (size_t)(dst*C + c)*3;
        atomAddF(ap+0, w3xs*y0); atomAddF(ap+1, w3xs*y1); atomAddF(ap+2, w3xs*y2);
      } else {
        float* ap = agg_v + (size_t)(dst*C + c)*3;
        atomAddF(ap+0, a[ci]*xv0); atomAddF(ap+1, a[ci]*xv1); atomAddF(ap+2, a[ci]*xv2);
      }
    }
  }
}

__global__ __launch_bounds__(256) void k_node_update_fb(
    const float* __restrict__ agg_sf, const float* __restrict__ agg_sg,
    const float* __restrict__ agg_v,
    const float* __restrict__ Wss, const float* __restrict__ bss,
    const float* __restrict__ Wvv,
    float* __restrict__ s_new, float* __restrict__ v_new,
    double* __restrict__ bn_sums)
{
  __shared__ float lacc[3*C];
  int t = blockIdx.x * 256 + threadIdx.x;
  int n = t >> 5;
  int c = t & 31;
  if (threadIdx.x < 3*C) lacc[threadIdx.x] = 0.0f;
  __syncthreads();
  float asf = agg_sf[n*C + c];
  float asg = agg_sg[n*C + c];
  const float* ap = agg_v + (size_t)(n*C + c)*3;
  float av0 = ap[0], av1 = ap[1], av2 = ap[2];
  float sgv = silu_f(asf);
  float gate = sigmoid_f(asg);
  float vg0 = gate*av0, vg1 = gate*av1, vg2 = gate*av2;
  float sn = bss[c];
  float vm0 = 0.0f, vm1 = 0.0f, vm2 = 0.0f;
  #pragma unroll
  for (int k = 0; k < C; k++) {
    float a  = __shfl(sgv, k, 32);
    sn = fmaf(a, Wss[k*C + c], sn);
    float wv = Wvv[k*C + c];
    vm0 = fmaf(__shfl(vg0, k, 32), wv, vm0);
    vm1 = fmaf(__shfl(vg1, k, 32), wv, vm1);
    vm2 = fmaf(__shfl(vg2, k, 32), wv, vm2);
  }
  s_new[n*C + c] = sn;
  float* vo = v_new + (size_t)(n*C + c)*3;
  vo[0] = vm0; vo[1] = vm1; vo[2] = vm2;
  float vn2 = vm0*vm0 + vm1*vm1 + vm2*vm2;
  atomicAdd(&lacc[c], sn);
  atomicAdd(&lacc[C + c], sn*sn);
  atomicAdd(&lacc[2*C + c], vn2);
  __syncthreads();
  if (threadIdx.x < 3*C) atomAddD(&bn_sums[threadIdx.x], (double)lacc[threadIdx.x]);
}

__global__ void k_bn_scales_fb(const double* __restrict__ bn_sums,
                               const float* __restrict__ gs, const float* __restrict__ gv,
                               float* __restrict__ scales)
{
  int m = threadIdx.x;
  if (m >= C) return;
  double S1 = bn_sums[m], S2 = bn_sums[C + m], VN = bn_sums[2*C + m];
  double mu  = S1 / (double)N_NODES;
  double var = S2 / (double)N_NODES - mu*mu;
  double vn2 = VN / (3.0 * (double)N_NODES);
  scales[m]       = (float)mu;
  scales[C + m]   = gs[m] / sqrtf((float)var + EPSF);
  scales[2*C + m] = gv[m] / sqrtf((float)vn2 + EPSF);
}

__global__ __launch_bounds__(256) void k_apply_fb(
    const float* __restrict__ s_new, const float* __restrict__ v_new,
    const float* __restrict__ scales, const float* __restrict__ bn_bs,
    float* __restrict__ s, float* __restrict__ v)
{
  int i = blockIdx.x * 256 + threadIdx.x;
  if (i >= N_NODES * C) return;
  int c = i & 31;
  s[i] += (s_new[i] - scales[c]) * scales[C + c] + bn_bs[c];
  float vs = scales[2*C + c];
  v[(size_t)i*3+0] += v_new[(size_t)i*3+0] * vs;
  v[(size_t)i*3+1] += v_new[(size_t)i*3+1] * vs;
  v[(size_t)i*3+2] += v_new[(size_t)i*3+2] * vs;
}

extern "C" void kernel_launch(void* const* d_in, const int* in_sizes, int n_in,
                              void* d_out, int out_size, void* d_ws, size_t ws_size,
                              hipStream_t stream)
{
  const int*   species  = (const int*)  d_in[0];
  const float* pos      = (const float*)d_in[1];
  const int*   ei       = (const int*)  d_in[2];
  const int*   batch    = (const int*)  d_in[3];
  const float* emb      = (const float*)d_in[4];
  const float* freqs    = (const float*)d_in[5];
  const float* rW1      = (const float*)d_in[6];
  const float* rb1      = (const float*)d_in[7];
  const float* rW2      = (const float*)d_in[8];
  const float* rb2      = (const float*)d_in[9];
  const float* rW3      = (const float*)d_in[10];
  const float* rb3      = (const float*)d_in[11];
  const float* Wss      = (const float*)d_in[12];
  const float* bss      = (const float*)d_in[13];
  const float* Wvv      = (const float*)d_in[14];
  const float* bn_gs    = (const float*)d_in[15];
  const float* bn_bs    = (const float*)d_in[16];
  const float* bn_gv    = (const float*)d_in[17];
  const float* W_out    = (const float*)d_in[18];
  const float* b_out    = (const float*)d_in[19];
  const float* atom_ref = (const float*)d_in[20];

  float* ws = (float*)d_ws;
  size_t off = 0;
  float* basis  = ws + off; off += (size_t)N_EDGES * NB;     // fb path only
  float* Y1     = ws + off; off += (size_t)N_EDGES * 3;      // fb path only
  float* s      = ws + off; off += (size_t)N_NODES * C;
  float* v      = ws + off; off += (size_t)N_NODES * C * 3;
  float* s_new  = ws + off; off += (size_t)N_NODES * C;
  float* v_new  = ws + off; off += (size_t)N_NODES * C * 3;
  double* bn_sums = (double*)(ws + off); off += 192;
  float* scales = ws + off; off += 96;

  // --- region A (sorted + table path) ---
  size_t ra = off;
  float* rec      = ws + ra;            ra += (size_t)N_EDGES * 8;
  int*   counts   = (int*)(ws + ra);    ra += N_NODES;
  int*   row_start= (int*)(ws + ra);    ra += N_NODES;
  int*   cursor   = (int*)(ws + ra);    ra += N_NODES;
  int*   bsum     = (int*)(ws + ra);    ra += 256;
  float* h2tab    = ws + ra;            ra += (size_t)NL * TBL * HID;
  float* wtab     = ws + ra;            ra += (size_t)NL * TBL * 128;
  unsigned short* s_bf = (unsigned short*)(ws + ra); ra += (size_t)N_NODES * C / 2;
  unsigned short* v_bf = (unsigned short*)(ws + ra); ra += (size_t)N_NODES * C * 3 / 2;
  size_t req_sorted = ra * 4;

  // --- region B (fallback atomic path, aliases region A) ---
  size_t rb = off;
  float* agg_sf = ws + rb; rb += (size_t)N_NODES * C;
  float* agg_sg = ws + rb; rb += (size_t)N_NODES * C;
  float* agg_v  = ws + rb; rb += (size_t)N_NODES * C * 3;

  dim3 b256(256);
  const int gE  = (N_EDGES + 255) / 256;
  const int gNC = (N_NODES * C + 255) / 256;
  const int gN  = (N_NODES + 255) / 256;

  hipMemsetAsync(v, 0, (size_t)N_NODES * C * 3 * sizeof(float), stream);

  if (ws_size >= req_sorted) {
    hipMemsetAsync(v_bf, 0, (size_t)N_NODES * C * 3 * sizeof(unsigned short), stream);
    hipMemsetAsync(counts, 0, N_NODES * sizeof(int), stream);
    hipMemsetAsync(cursor, 0, N_NODES * sizeof(int), stream);
    k_node_init<<<gNC, b256, 0, stream>>>(species, emb, s, s_bf);
    k_hist<<<gE, b256, 0, stream>>>(ei, counts);
    k_scanA<<<NBLK_N, b256, 0, stream>>>(counts, bsum);
    k_scanB<<<1, b256, 0, stream>>>(bsum);
    k_scanC<<<NBLK_N, b256, 0, stream>>>(counts, bsum, row_start);
    k_geom_scatter<<<gE, b256, 0, stream>>>(pos, ei, row_start, cursor, rec);
    k_table_h<<<(NL*TBL)/256, b256, 0, stream>>>(freqs, rW1, rb1, rW2, rb2, h2tab);
    k_table_w<<<(NL*TBL*16)/256, b256, 0, stream>>>(h2tab, rW3, rb3, wtab);

    for (int l = 0; l < NL; l++) {
      hipMemsetAsync(bn_sums, 0, 96 * sizeof(double), stream);
      k_agg_update<<<(N_NODES*C)/256, b256, 0, stream>>>(
          wtab + (size_t)l * TBL * 128, rec,
          row_start, counts, s_bf, v_bf, Wss + l*C*C, bss + l*C, Wvv + l*C*C,
          s_new, v_new);
      k_bn_stats<<<BN_BLOCKS, b256, 0, stream>>>(s_new, v_new, bn_sums);
      k_apply<<<gNC, b256, 0, stream>>>(s_new, v_new, bn_sums,
          bn_gs + l*C, bn_gv + l*C, bn_bs + l*C, s, v, s_bf, v_bf);
    }
  } else {
    k_node_init<<<gNC, b256, 0, stream>>>(species, emb, s, (unsigned short*)(ws + off));
    k_edge_geom<<<gE, b256, 0, stream>>>(pos, ei, freqs, basis, Y1);
    for (int l = 0; l < NL; l++) {
      hipMemsetAsync(agg_sf, 0, (size_t)N_NODES * 5 * C * sizeof(float), stream);
      hipMemsetAsync(bn_sums, 0, 96 * sizeof(double), stream);
      k_edge_msg_fb<<<gE, b256, 0, stream>>>(basis, Y1, ei, s, v,
          rW1 + l*NB*HID, rb1 + l*HID, rW2 + l*HID*HID, rb2 + l*HID,
          rW3 + l*HID*4*C, rb3 + l*4*C, agg_sf, agg_sg, agg_v);
      k_node_update_fb<<<(N_NODES*C)/256, b256, 0, stream>>>(agg_sf, agg_sg, agg_v,
          Wss + l*C*C, bss + l*C, Wvv + l*C*C, s_new, v_new, bn_sums);
      k_bn_scales_fb<<<1, 64, 0, stream>>>(bn_sums, bn_gs + l*C, bn_gv + l*C, scales);
      k_apply_fb<<<gNC, b256, 0, stream>>>(s_new, v_new, scales, bn_bs + l*C, s, v);
    }
  }

  hipMemsetAsync(d_out, 0, NG * sizeof(float), stream);
  k_readout<<<gN, b256, 0, stream>>>(s, species, batch, W_out, b_out, atom_ref, (float*)d_out);
}